// Round 12
// baseline (301.344 us; speedup 1.0000x reference)
//
#include <hip/hip_runtime.h>
#include <cstddef>

// SASRec inference. Round 12: MEASUREMENT + small win.
// (a) k_embed fused into k_layers phase 0 (bit-identical math, -16MB traffic,
//     -1 launch);  (b) k_score reverted to exact R9 (best: 197.5us);
// (c) k_score launched TWICE (idempotent) -> total-time delta measures
//     k_score's true duration, settling the k_score-vs-k_layers attribution.

#define NITEMS 200000
#define Bsz 512
#define Ssz 64
#define Dsz 64
#define EPSV 1e-3f
#define NEGV (-4294967295.0f)   // -2^32 + 1

typedef __attribute__((ext_vector_type(8))) short short8;   // 8 bf16
typedef __attribute__((ext_vector_type(4))) float f32x4;
typedef unsigned short ushort_t;
typedef unsigned long long u64_t;

static __device__ __forceinline__ float wsum(float v){
#pragma unroll
  for (int o = 32; o > 0; o >>= 1) v += __shfl_xor(v, o, 64);
  return v;
}
static __device__ __forceinline__ float wmax(float v){
#pragma unroll
  for (int o = 32; o > 0; o >>= 1) v = fmaxf(v, __shfl_xor(v, o, 64));
  return v;
}

// bf16 round-to-nearest-even (finite inputs only)
static __device__ __forceinline__ ushort_t f2b(float f){
  unsigned u = __float_as_uint(f);
  unsigned r = u + 0x7fffu + ((u >> 16) & 1u);
  return (ushort_t)(r >> 16);
}
static __device__ __forceinline__ float b2f(ushort_t h){
  return __uint_as_float(((unsigned)h) << 16);
}

// ------------------------------------------------------ fused block layers --
static __device__ __forceinline__ void stage_w1024(ushort_t WH[64][72],
    ushort_t WL[64][72], float4 r0, int t){
  __syncthreads();                 // fence previous consumers of WH/WL
  int k0 = t >> 4, n0 = (t & 15) * 4;
  float f0[4] = {r0.x, r0.y, r0.z, r0.w};
#pragma unroll
  for (int j = 0; j < 4; ++j){
    ushort_t h = f2b(f0[j]);
    WH[n0 + j][k0] = h;
    WL[n0 + j][k0] = f2b(f0[j] - b2f(h));
  }
  __syncthreads();
}

static __device__ __forceinline__ void mm16(
    const ushort_t (*__restrict__ Ah)[72], const ushort_t (*__restrict__ Al)[72],
    const ushort_t (*__restrict__ Bh)[72], const ushort_t (*__restrict__ Bl)[72],
    int qb, int cb, int li, int g, f32x4& acc){
  acc = (f32x4)(0.f);
#pragma unroll
  for (int kc = 0; kc < 2; ++kc){
    short8 ah = *(const short8*)&Ah[qb*16 + li][kc*32 + g*8];
    short8 al = *(const short8*)&Al[qb*16 + li][kc*32 + g*8];
    short8 bh = *(const short8*)&Bh[cb*16 + li][kc*32 + g*8];
    short8 bl = *(const short8*)&Bl[cb*16 + li][kc*32 + g*8];
    acc = __builtin_amdgcn_mfma_f32_16x16x32_bf16(ah, bh, acc, 0, 0, 0);
    acc = __builtin_amdgcn_mfma_f32_16x16x32_bf16(ah, bl, acc, 0, 0, 0);
    acc = __builtin_amdgcn_mfma_f32_16x16x32_bf16(al, bh, acc, 0, 0, 0);
  }
}

__global__ __launch_bounds__(1024) void k_layers(const int* __restrict__ ids,
    const float* __restrict__ item_emb, const float* __restrict__ pos_emb,
    const float* __restrict__ ln1g, const float* __restrict__ ln1b,
    const float* __restrict__ Wq, const float* __restrict__ bq,
    const float* __restrict__ Wk, const float* __restrict__ bk,
    const float* __restrict__ Wv, const float* __restrict__ bv,
    const float* __restrict__ ln2g, const float* __restrict__ ln2b,
    const float* __restrict__ W1, const float* __restrict__ b1,
    const float* __restrict__ W2, const float* __restrict__ b2,
    const float* __restrict__ lnfg, const float* __restrict__ lnfb,
    ushort_t* __restrict__ Eh, ushort_t* __restrict__ El){
  __shared__ float F0[64][68];   // seq -> scores -> x -> layer-out (f32)
  __shared__ float F1[64][68];   // LN1/LN2 residuals
  __shared__ ushort_t UH[5][64][72], UL[5][64][72];
  __shared__ ushort_t WH[64][72], WL[64][72];
  __shared__ float s_msk[64];

  const int t = threadIdx.x;
  const int lane = t & 63, wid = t >> 6;        // 16 waves
  const int li = lane & 15, g = lane >> 4;
  const int qb = wid & 3, cb = wid >> 2;
  const int b = blockIdx.x;

  // ---- phase 0 (fused embed): gather + pos + mask -> F0 (f32) + U0 ----
  {
    int r = t >> 4, c4 = t & 15, c = c4 * 4;
    int id = ids[b * Ssz + r];
    float4 v = make_float4(0.f, 0.f, 0.f, 0.f);
    if (id != NITEMS){
      float4 a = ((const float4*)(item_emb + (size_t)id * 64))[c4];
      float4 p = ((const float4*)(pos_emb + r * 64))[c4];
      v = make_float4(a.x + p.x, a.y + p.y, a.z + p.z, a.w + p.w);
    }
    *(float4*)&F0[r][c] = v;
    float f[4] = {v.x, v.y, v.z, v.w};
#pragma unroll
    for (int j = 0; j < 4; ++j){
      ushort_t h = f2b(f[j]);
      UH[0][r][c + j] = h;
      UL[0][r][c + j] = f2b(f[j] - b2f(h));
    }
  }
  if (t < 64) s_msk[t] = (ids[b * Ssz + t] != NITEMS) ? 1.f : 0.f;

  const int k0 = t >> 4, n0 = (t & 15) * 4;

  for (int l = 0; l < 2; ++l){
    float4 w_q = *(const float4*)&Wq[l*4096 + k0*64 + n0];
    float4 w_k = *(const float4*)&Wk[l*4096 + k0*64 + n0];
    float4 w_v = *(const float4*)&Wv[l*4096 + k0*64 + n0];
    float4 w_1 = *(const float4*)&W1[l*4096 + k0*64 + n0];
    float4 w_2 = *(const float4*)&W2[l*4096 + k0*64 + n0];

    __syncthreads();

    // ---- LN1 ----
    for (int r = wid; r < 64; r += 16){
      float x = F0[r][lane];
      float mu = wsum(x) * (1.f / 64.f);
      float dv = x - mu;
      float var = wsum(dv * dv) * (1.f / 64.f);
      float o = dv * (1.f / sqrtf(var + EPSV)) * ln1g[l*64 + lane] + ln1b[l*64 + lane];
      F1[r][lane] = o;
      ushort_t h = f2b(o);
      UH[1][r][lane] = h;
      UL[1][r][lane] = f2b(o - b2f(h));
    }

    // ---- Q ----
    stage_w1024(WH, WL, w_q, t);
    { f32x4 acc; mm16(UH[1], UL[1], WH, WL, qb, cb, li, g, acc);
      int col = cb*16 + li;
      float bb = bq[l*64 + col];
#pragma unroll
      for (int r4 = 0; r4 < 4; ++r4){
        int row = qb*16 + g*4 + r4;
        float qv = acc[r4] + bb;
        ushort_t h = f2b(qv);
        UH[2][row][col] = h; UL[2][row][col] = f2b(qv - b2f(h));
      }
    }
    // ---- K ----
    stage_w1024(WH, WL, w_k, t);
    { f32x4 acc; mm16(UH[0], UL[0], WH, WL, qb, cb, li, g, acc);
      int col = cb*16 + li;
      float bb = bk[l*64 + col];
#pragma unroll
      for (int r4 = 0; r4 < 4; ++r4){
        int row = qb*16 + g*4 + r4;
        float kv = acc[r4] + bb;
        ushort_t h = f2b(kv);
        UH[3][row][col] = h; UL[3][row][col] = f2b(kv - b2f(h));
      }
    }
    // ---- V (transposed) ----
    stage_w1024(WH, WL, w_v, t);
    { f32x4 acc; mm16(UH[0], UL[0], WH, WL, qb, cb, li, g, acc);
      int col = cb*16 + li;
      float bb = bv[l*64 + col];
#pragma unroll
      for (int r4 = 0; r4 < 4; ++r4){
        int row = qb*16 + g*4 + r4;
        float vv = acc[r4] + bb;
        ushort_t h = f2b(vv);
        UH[4][col][row] = h; UL[4][col][row] = f2b(vv - b2f(h));
      }
    }
    __syncthreads();

    // ---- scores ----
    { f32x4 acc; mm16(UH[2], UL[2], UH[3], UL[3], qb, cb, li, g, acc);
      int col = cb*16 + li;
#pragma unroll
      for (int r4 = 0; r4 < 4; ++r4)
        F0[qb*16 + g*4 + r4][col] = acc[r4];
    }
    __syncthreads();

    // ---- masked softmax ----
    for (int r = wid; r < 64; r += 16){
      float raw = F0[r][lane];
      bool valid = (lane <= r) && (s_msk[lane] != 0.f);
      float sc = valid ? raw * 0.125f : NEGV;
      float m = wmax(sc);
      float e = __expf(sc - m);
      float ssumv = wsum(e);
      float p = (e / ssumv) * s_msk[r];
      ushort_t h = f2b(p);
      UH[0][r][lane] = h;
      UL[0][r][lane] = f2b(p - b2f(h));
    }
    __syncthreads();

    // ---- x = P @ V + xq ----
    { f32x4 acc; mm16(UH[0], UL[0], UH[4], UL[4], qb, cb, li, g, acc);
      int col = cb*16 + li;
#pragma unroll
      for (int r4 = 0; r4 < 4; ++r4){
        int row = qb*16 + g*4 + r4;
        F0[row][col] = acc[r4] + F1[row][col];
      }
    }
    __syncthreads();

    // ---- LN2 ----
    for (int r = wid; r < 64; r += 16){
      float x = F0[r][lane];
      float mu = wsum(x) * (1.f / 64.f);
      float dv = x - mu;
      float var = wsum(dv * dv) * (1.f / 64.f);
      float o = dv * (1.f / sqrtf(var + EPSV)) * ln2g[l*64 + lane] + ln2b[l*64 + lane];
      F1[r][lane] = o;
      ushort_t h = f2b(o);
      UH[1][r][lane] = h;
      UL[1][r][lane] = f2b(o - b2f(h));
    }
    // ---- FFN hidden ----
    stage_w1024(WH, WL, w_1, t);
    { f32x4 acc; mm16(UH[1], UL[1], WH, WL, qb, cb, li, g, acc);
      int col = cb*16 + li;
      float bb = b1[l*64 + col];
#pragma unroll
      for (int r4 = 0; r4 < 4; ++r4){
        int row = qb*16 + g*4 + r4;
        float hv = fmaxf(acc[r4] + bb, 0.f);
        ushort_t h = f2b(hv);
        UH[2][row][col] = h; UL[2][row][col] = f2b(hv - b2f(h));
      }
    }
    // ---- layer out -> F0 (+ U0 for next layer) ----
    stage_w1024(WH, WL, w_2, t);
    { f32x4 acc; mm16(UH[2], UL[2], WH, WL, qb, cb, li, g, acc);
      int col = cb*16 + li;
      float bb = b2[l*64 + col];
#pragma unroll
      for (int r4 = 0; r4 < 4; ++r4){
        int row = qb*16 + g*4 + r4;
        float o = (acc[r4] + bb + F1[row][col]) * s_msk[row];
        F0[row][col] = o;
        if (l == 0){
          ushort_t h = f2b(o);
          UH[0][row][col] = h; UL[0][row][col] = f2b(o - b2f(h));
        }
      }
    }
  }

  // ---- fused final LN on row 63 -> packed bf16 hi/lo E ----
  __syncthreads();
  if (wid == 0){
    float x = F0[63][lane];
    float mu = wsum(x) * (1.f / 64.f);
    float dv = x - mu;
    float var = wsum(dv * dv) * (1.f / 64.f);
    float o = dv * (1.f / sqrtf(var + EPSV)) * lnfg[lane] + lnfb[lane];
    ushort_t h = f2b(o);
    Eh[b * 64 + lane] = h;
    El[b * 64 + lane] = f2b(o - b2f(h));
  }
}

// --------------------------------------------------------------- scoring ---
// Exact R9 kernel (best config). Idempotent: launched twice for measurement.
#define LOADA(DH, DL, c) { int er = (c)*64 + w*16 + li;                 \
  DH[0] = *(const short8*)&Eh[er*64 + g*8];                             \
  DH[1] = *(const short8*)&Eh[er*64 + 32 + g*8];                        \
  DL[0] = *(const short8*)&El[er*64 + g*8];                             \
  DL[1] = *(const short8*)&El[er*64 + 32 + g*8]; }

#define CHUNK(c, CAh, CAl, NAh, NAl, PF) {                              \
  if (PF) LOADA(NAh, NAl, (c)+1);                                       \
  f32x4 acc[8];                                                         \
  _Pragma("unroll") for (int nt = 0; nt < 8; ++nt) acc[nt] = (f32x4)(0.f); \
  _Pragma("unroll") for (int kc = 0; kc < 2; ++kc){                     \
    _Pragma("unroll") for (int nt = 0; nt < 8; ++nt){                   \
      short8 bh = TB[nt*2 + kc][lane];                                  \
      short8 bl = TB[16 + nt*2 + kc][lane];                             \
      acc[nt] = __builtin_amdgcn_mfma_f32_16x16x32_bf16(CAh[kc], bh, acc[nt], 0, 0, 0); \
      acc[nt] = __builtin_amdgcn_mfma_f32_16x16x32_bf16(CAh[kc], bl, acc[nt], 0, 0, 0); \
      acc[nt] = __builtin_amdgcn_mfma_f32_16x16x32_bf16(CAl[kc], bh, acc[nt], 0, 0, 0); \
    }}                                                                  \
  _Pragma("unroll") for (int nt = 0; nt < 8; ++nt)                      \
    _Pragma("unroll") for (int r = 0; r < 4; ++r)                       \
      TT[w][g*4 + r][nt*16 + li] = acc[nt][r];                          \
  asm volatile("s_waitcnt lgkmcnt(0)" ::: "memory");                    \
  __builtin_amdgcn_sched_barrier(0);                                    \
  _Pragma("unroll") for (int k = 0; k < 4; ++k){                        \
    int rr = 4*k + g;                                                   \
    size_t rb = (size_t)((c)*64 + w*16 + rr) * NITEMS;                  \
    _Pragma("unroll") for (int h2 = 0; h2 < 2; ++h2){                   \
      int col = i0 + li*8 + h2*4;                                       \
      if (col < NITEMS)                                                 \
        *(float4*)&out[rb + col] = *(const float4*)&TT[w][rr][li*8 + h2*4]; \
    }}                                                                  \
  __builtin_amdgcn_sched_barrier(0); }

__global__ __launch_bounds__(256) void k_score(
    const ushort_t* __restrict__ Eh, const ushort_t* __restrict__ El,
    const float* __restrict__ T, float* __restrict__ out){
  __shared__ short8 TB[32][64];     // 32 KB: frag-ordered T tile (hi/lo)
  __shared__ float TT[4][16][132];  // 33 KB: per-wave transpose tiles
  const int t = threadIdx.x, lane = t & 63, w = t >> 6;  // 4 waves
  const int li = lane & 15, g = lane >> 4;
  const int i0 = blockIdx.x * 128;

  // ---- stage T tile (128 rows) into LDS fragment order, hi/lo bf16 ----
#pragma unroll
  for (int i = 0; i < 8; ++i){
    int e4 = t + 256 * i;            // [128 rows][16 float4-cols]
    int r = e4 >> 4, c4 = e4 & 15;
    int gi = i0 + r;
    float4 v = make_float4(0.f, 0.f, 0.f, 0.f);
    if (gi < NITEMS) v = ((const float4*)(T + (size_t)gi * 64))[c4];
    int nt = r >> 4, li2 = r & 15;
    int kc = c4 >> 3, g2 = (c4 >> 1) & 3, j0 = (c4 & 1) * 4;
    float f[4] = {v.x, v.y, v.z, v.w};
    u64_t ph = 0, pl = 0;
#pragma unroll
    for (int j = 0; j < 4; ++j){
      ushort_t hh = f2b(f[j]);
      ushort_t ll = f2b(f[j] - b2f(hh));
      ph |= (u64_t)hh << (16*j);
      pl |= (u64_t)ll << (16*j);
    }
    *(u64_t*)((ushort_t*)&TB[nt*2 + kc][g2*16 + li2] + j0) = ph;
    *(u64_t*)((ushort_t*)&TB[16 + nt*2 + kc][g2*16 + li2] + j0) = pl;
  }
  __syncthreads();

  // ---- 8 batch chunks, A double-buffered ----
  short8 Ah0[2], Al0[2], Ah1[2], Al1[2];
  LOADA(Ah0, Al0, 0);
  CHUNK(0, Ah0, Al0, Ah1, Al1, 1)
  CHUNK(1, Ah1, Al1, Ah0, Al0, 1)
  CHUNK(2, Ah0, Al0, Ah1, Al1, 1)
  CHUNK(3, Ah1, Al1, Ah0, Al0, 1)
  CHUNK(4, Ah0, Al0, Ah1, Al1, 1)
  CHUNK(5, Ah1, Al1, Ah0, Al0, 1)
  CHUNK(6, Ah0, Al0, Ah1, Al1, 1)
  CHUNK(7, Ah1, Al1, Ah0, Al0, 0)
}

// ----------------------------------------------------------------- launch --
extern "C" void kernel_launch(void* const* d_in, const int* in_sizes, int n_in,
                              void* d_out, int out_size, void* d_ws, size_t ws_size,
                              hipStream_t stream){
  const int*   ids      = (const int*)  d_in[0];
  const float* item_emb = (const float*)d_in[1];
  const float* pos_emb  = (const float*)d_in[2];
  const float* ln1g     = (const float*)d_in[3];
  const float* ln1b     = (const float*)d_in[4];
  const float* Wq       = (const float*)d_in[5];
  const float* bq       = (const float*)d_in[6];
  const float* Wk       = (const float*)d_in[7];
  const float* bk       = (const float*)d_in[8];
  const float* Wv       = (const float*)d_in[9];
  const float* bv       = (const float*)d_in[10];
  const float* ln2g     = (const float*)d_in[11];
  const float* ln2b     = (const float*)d_in[12];
  const float* W1       = (const float*)d_in[13];
  const float* b1       = (const float*)d_in[14];
  const float* W2       = (const float*)d_in[15];
  const float* b2       = (const float*)d_in[16];
  const float* lnfg     = (const float*)d_in[17];
  const float* lnfb     = (const float*)d_in[18];
  const float* items    = (const float*)d_in[19];
  float* out = (float*)d_out;

  ushort_t* Ehp = (ushort_t*)d_ws;          // 64 KB
  ushort_t* Elp = Ehp + 512 * 64;           // 64 KB

  k_layers<<<Bsz, 1024, 0, stream>>>(ids, item_emb, pos_emb,
      ln1g, ln1b, Wq, bq, Wk, bk, Wv, bv,
      ln2g, ln2b, W1, b1, W2, b2, lnfg, lnfb, Ehp, Elp);
  // k_score launched twice (idempotent): delta vs single-launch baseline
  // (~193us expected) directly measures k_score's duration.
  k_score<<<1563, 256, 0, stream>>>(Ehp, Elp, items, out);
  k_score<<<1563, 256, 0, stream>>>(Ehp, Elp, items, out);
}

// Round 13
// 199.248 us; speedup vs baseline: 1.5124x; 1.5124x over previous
//
#include <hip/hip_runtime.h>
#include <cstddef>

// SASRec inference. Round 13: k_layers rewritten — all intermediates in f32
// LDS only (5 buffers); bf16 hi/lo fragments converted IN REGISTERS at load
// time (bit-identical values); weights loaded straight from global into
// register fragments (no LDS staging). Barriers 17 -> 8 per layer.
// k_score = exact R9 (best known), single launch.

#define NITEMS 200000
#define Bsz 512
#define Ssz 64
#define Dsz 64
#define EPSV 1e-3f
#define NEGV (-4294967295.0f)   // -2^32 + 1

typedef __attribute__((ext_vector_type(8))) short short8;   // 8 bf16
typedef __attribute__((ext_vector_type(4))) float f32x4;
typedef unsigned short ushort_t;
typedef unsigned long long u64_t;

static __device__ __forceinline__ float wsum(float v){
#pragma unroll
  for (int o = 32; o > 0; o >>= 1) v += __shfl_xor(v, o, 64);
  return v;
}
static __device__ __forceinline__ float wmax(float v){
#pragma unroll
  for (int o = 32; o > 0; o >>= 1) v = fmaxf(v, __shfl_xor(v, o, 64));
  return v;
}

// bf16 round-to-nearest-even (finite inputs only)
static __device__ __forceinline__ ushort_t f2b(float f){
  unsigned u = __float_as_uint(f);
  unsigned r = u + 0x7fffu + ((u >> 16) & 1u);
  return (ushort_t)(r >> 16);
}
static __device__ __forceinline__ float b2f(ushort_t h){
  return __uint_as_float(((unsigned)h) << 16);
}

// 8 consecutive f32 -> bf16 hi/lo fragments (in registers)
static __device__ __forceinline__ void a_frag(const float* __restrict__ p,
    short8& h8, short8& l8){
  float4 v0 = *(const float4*)p, v1 = *(const float4*)(p + 4);
  float f[8] = {v0.x,v0.y,v0.z,v0.w,v1.x,v1.y,v1.z,v1.w};
#pragma unroll
  for (int j = 0; j < 8; ++j){
    ushort_t hh = f2b(f[j]);
    h8[j] = (short)hh;
    l8[j] = (short)f2b(f[j] - b2f(hh));
  }
}

// weight B-fragment straight from global: rows n=cb*16+li of W^T, k-slices
static __device__ __forceinline__ void w_frag(const float* __restrict__ Wg,
    int cb, int li, int g, short8 bh[2], short8 bl[2]){
#pragma unroll
  for (int kc = 0; kc < 2; ++kc){
    float f[8];
#pragma unroll
    for (int j = 0; j < 8; ++j)
      f[j] = Wg[(kc*32 + g*8 + j)*64 + cb*16 + li];
    short8 h, l;
#pragma unroll
    for (int j = 0; j < 8; ++j){
      ushort_t hh = f2b(f[j]);
      h[j] = (short)hh;
      l[j] = (short)f2b(f[j] - b2f(hh));
    }
    bh[kc] = h; bl[kc] = l;
  }
}

// GEMM tile vs register weight frags: A from f32 LDS
static __device__ __forceinline__ void mmW(const float (*__restrict__ A)[68],
    const short8 bh[2], const short8 bl[2], int qb, int li, int g, f32x4& acc){
  acc = (f32x4)(0.f);
#pragma unroll
  for (int kc = 0; kc < 2; ++kc){
    short8 ah, al;
    a_frag(&A[qb*16 + li][kc*32 + g*8], ah, al);
    acc = __builtin_amdgcn_mfma_f32_16x16x32_bf16(ah, bh[kc], acc, 0, 0, 0);
    acc = __builtin_amdgcn_mfma_f32_16x16x32_bf16(ah, bl[kc], acc, 0, 0, 0);
    acc = __builtin_amdgcn_mfma_f32_16x16x32_bf16(al, bh[kc], acc, 0, 0, 0);
  }
}

// GEMM tile with both operands from f32 LDS (QK^T, PV)
static __device__ __forceinline__ void mmA(const float (*__restrict__ A)[68],
    const float (*__restrict__ B)[68], int qb, int cb, int li, int g, f32x4& acc){
  acc = (f32x4)(0.f);
#pragma unroll
  for (int kc = 0; kc < 2; ++kc){
    short8 ah, al, bh, bl;
    a_frag(&A[qb*16 + li][kc*32 + g*8], ah, al);
    a_frag(&B[cb*16 + li][kc*32 + g*8], bh, bl);
    acc = __builtin_amdgcn_mfma_f32_16x16x32_bf16(ah, bh, acc, 0, 0, 0);
    acc = __builtin_amdgcn_mfma_f32_16x16x32_bf16(ah, bl, acc, 0, 0, 0);
    acc = __builtin_amdgcn_mfma_f32_16x16x32_bf16(al, bh, acc, 0, 0, 0);
  }
}

// ------------------------------------------------------ fused block layers --
__global__ __launch_bounds__(1024) void k_layers(const int* __restrict__ ids,
    const float* __restrict__ item_emb, const float* __restrict__ pos_emb,
    const float* __restrict__ ln1g, const float* __restrict__ ln1b,
    const float* __restrict__ Wq, const float* __restrict__ bq,
    const float* __restrict__ Wk, const float* __restrict__ bk,
    const float* __restrict__ Wv, const float* __restrict__ bv,
    const float* __restrict__ ln2g, const float* __restrict__ ln2b,
    const float* __restrict__ W1, const float* __restrict__ b1,
    const float* __restrict__ W2, const float* __restrict__ b2,
    const float* __restrict__ lnfg, const float* __restrict__ lnfb,
    ushort_t* __restrict__ Eh, ushort_t* __restrict__ El){
  __shared__ float B0[64][68];   // seq -> scores -> P -> (next) seq
  __shared__ float B1[64][68];   // xq (LN1 out) -> res (LN2 out)
  __shared__ float B2[64][68];   // Q -> x (attn+residual)
  __shared__ float B3[64][68];   // K -> FFN hidden
  __shared__ float B4[64][68];   // V^T
  __shared__ float s_msk[64];

  const int t = threadIdx.x;
  const int lane = t & 63, wid = t >> 6;        // 16 waves
  const int li = lane & 15, g = lane >> 4;
  const int qb = wid & 3, cb = wid >> 2;
  const int b = blockIdx.x;

  // ---- phase 0 (fused embed): gather + pos + mask -> B0 (f32) ----
  {
    int r = t >> 4, c4 = t & 15, c = c4 * 4;
    int id = ids[b * Ssz + r];
    float4 v = make_float4(0.f, 0.f, 0.f, 0.f);
    if (id != NITEMS){
      float4 a = ((const float4*)(item_emb + (size_t)id * 64))[c4];
      float4 p = ((const float4*)(pos_emb + r * 64))[c4];
      v = make_float4(a.x + p.x, a.y + p.y, a.z + p.z, a.w + p.w);
    }
    *(float4*)&B0[r][c] = v;
  }
  if (t < 64) s_msk[t] = (ids[b * Ssz + t] != NITEMS) ? 1.f : 0.f;

  for (int l = 0; l < 2; ++l){
    __syncthreads();   // fences phase-0 (l=0) / previous layer-out (l=1)

    // ---- LN1: B0 -> B1 ----
    for (int r = wid; r < 64; r += 16){
      float x = B0[r][lane];
      float mu = wsum(x) * (1.f / 64.f);
      float dv = x - mu;
      float var = wsum(dv * dv) * (1.f / 64.f);
      B1[r][lane] = dv * (1.f / sqrtf(var + EPSV)) * ln1g[l*64 + lane] + ln1b[l*64 + lane];
    }
    __syncthreads();

    // ---- Q = LN1 @ Wq + bq -> B2 ; K = seq @ Wk + bk -> B3 ;
    //      V = seq @ Wv + bv -> B4 transposed. One barrier after all three.
    { short8 bh[2], bl[2]; w_frag(Wq + l*4096, cb, li, g, bh, bl);
      f32x4 acc; mmW(B1, bh, bl, qb, li, g, acc);
      int col = cb*16 + li; float bb = bq[l*64 + col];
#pragma unroll
      for (int r4 = 0; r4 < 4; ++r4) B2[qb*16 + g*4 + r4][col] = acc[r4] + bb;
    }
    { short8 bh[2], bl[2]; w_frag(Wk + l*4096, cb, li, g, bh, bl);
      f32x4 acc; mmW(B0, bh, bl, qb, li, g, acc);
      int col = cb*16 + li; float bb = bk[l*64 + col];
#pragma unroll
      for (int r4 = 0; r4 < 4; ++r4) B3[qb*16 + g*4 + r4][col] = acc[r4] + bb;
    }
    { short8 bh[2], bl[2]; w_frag(Wv + l*4096, cb, li, g, bh, bl);
      f32x4 acc; mmW(B0, bh, bl, qb, li, g, acc);
      int col = cb*16 + li; float bb = bv[l*64 + col];
#pragma unroll
      for (int r4 = 0; r4 < 4; ++r4) B4[col][qb*16 + g*4 + r4] = acc[r4] + bb;
    }
    __syncthreads();

    // ---- scores = Q @ K^T -> B0 (seq dead) ----
    { f32x4 acc; mmA(B2, B3, qb, cb, li, g, acc);
      int col = cb*16 + li;
#pragma unroll
      for (int r4 = 0; r4 < 4; ++r4) B0[qb*16 + g*4 + r4][col] = acc[r4];
    }
    __syncthreads();

    // ---- masked softmax in place: B0 -> B0 (P) ----
    for (int r = wid; r < 64; r += 16){
      float raw = B0[r][lane];
      bool valid = (lane <= r) && (s_msk[lane] != 0.f);
      float sc = valid ? raw * 0.125f : NEGV;
      float m = wmax(sc);
      float e = __expf(sc - m);
      float ssumv = wsum(e);
      B0[r][lane] = (e / ssumv) * s_msk[r];
    }
    __syncthreads();

    // ---- x = P @ V + xq -> B2 (Q dead) ----
    { f32x4 acc; mmA(B0, B4, qb, cb, li, g, acc);
      int col = cb*16 + li;
#pragma unroll
      for (int r4 = 0; r4 < 4; ++r4){
        int row = qb*16 + g*4 + r4;
        B2[row][col] = acc[r4] + B1[row][col];
      }
    }
    __syncthreads();

    // ---- LN2: B2 -> B1 (xq dead) ----
    for (int r = wid; r < 64; r += 16){
      float x = B2[r][lane];
      float mu = wsum(x) * (1.f / 64.f);
      float dv = x - mu;
      float var = wsum(dv * dv) * (1.f / 64.f);
      B1[r][lane] = dv * (1.f / sqrtf(var + EPSV)) * ln2g[l*64 + lane] + ln2b[l*64 + lane];
    }
    __syncthreads();

    // ---- h = relu(res @ W1 + b1) -> B3 (K dead) ----
    { short8 bh[2], bl[2]; w_frag(W1 + l*4096, cb, li, g, bh, bl);
      f32x4 acc; mmW(B1, bh, bl, qb, li, g, acc);
      int col = cb*16 + li; float bb = b1[l*64 + col];
#pragma unroll
      for (int r4 = 0; r4 < 4; ++r4)
        B3[qb*16 + g*4 + r4][col] = fmaxf(acc[r4] + bb, 0.f);
    }
    __syncthreads();

    // ---- out = (h @ W2 + b2 + res) * mask -> B0 (next seq) ----
    { short8 bh[2], bl[2]; w_frag(W2 + l*4096, cb, li, g, bh, bl);
      f32x4 acc; mmW(B3, bh, bl, qb, li, g, acc);
      int col = cb*16 + li; float bb = b2[l*64 + col];
#pragma unroll
      for (int r4 = 0; r4 < 4; ++r4){
        int row = qb*16 + g*4 + r4;
        B0[row][col] = (acc[r4] + bb + B1[row][col]) * s_msk[row];
      }
    }
  }

  // ---- fused final LN on row 63 -> packed bf16 hi/lo E ----
  __syncthreads();
  if (wid == 0){
    float x = B0[63][lane];
    float mu = wsum(x) * (1.f / 64.f);
    float dv = x - mu;
    float var = wsum(dv * dv) * (1.f / 64.f);
    float o = dv * (1.f / sqrtf(var + EPSV)) * lnfg[lane] + lnfb[lane];
    ushort_t h = f2b(o);
    Eh[b * 64 + lane] = h;
    El[b * 64 + lane] = f2b(o - b2f(h));
  }
}

// --------------------------------------------------------------- scoring ---
// Exact R9 kernel (best config), single launch.
#define LOADA(DH, DL, c) { int er = (c)*64 + w*16 + li;                 \
  DH[0] = *(const short8*)&Eh[er*64 + g*8];                             \
  DH[1] = *(const short8*)&Eh[er*64 + 32 + g*8];                        \
  DL[0] = *(const short8*)&El[er*64 + g*8];                             \
  DL[1] = *(const short8*)&El[er*64 + 32 + g*8]; }

#define CHUNK(c, CAh, CAl, NAh, NAl, PF) {                              \
  if (PF) LOADA(NAh, NAl, (c)+1);                                       \
  f32x4 acc[8];                                                         \
  _Pragma("unroll") for (int nt = 0; nt < 8; ++nt) acc[nt] = (f32x4)(0.f); \
  _Pragma("unroll") for (int kc = 0; kc < 2; ++kc){                     \
    _Pragma("unroll") for (int nt = 0; nt < 8; ++nt){                   \
      short8 bh = TB[nt*2 + kc][lane];                                  \
      short8 bl = TB[16 + nt*2 + kc][lane];                             \
      acc[nt] = __builtin_amdgcn_mfma_f32_16x16x32_bf16(CAh[kc], bh, acc[nt], 0, 0, 0); \
      acc[nt] = __builtin_amdgcn_mfma_f32_16x16x32_bf16(CAh[kc], bl, acc[nt], 0, 0, 0); \
      acc[nt] = __builtin_amdgcn_mfma_f32_16x16x32_bf16(CAl[kc], bh, acc[nt], 0, 0, 0); \
    }}                                                                  \
  _Pragma("unroll") for (int nt = 0; nt < 8; ++nt)                      \
    _Pragma("unroll") for (int r = 0; r < 4; ++r)                       \
      TT[w][g*4 + r][nt*16 + li] = acc[nt][r];                          \
  asm volatile("s_waitcnt lgkmcnt(0)" ::: "memory");                    \
  __builtin_amdgcn_sched_barrier(0);                                    \
  _Pragma("unroll") for (int k = 0; k < 4; ++k){                        \
    int rr = 4*k + g;                                                   \
    size_t rb = (size_t)((c)*64 + w*16 + rr) * NITEMS;                  \
    _Pragma("unroll") for (int h2 = 0; h2 < 2; ++h2){                   \
      int col = i0 + li*8 + h2*4;                                       \
      if (col < NITEMS)                                                 \
        *(float4*)&out[rb + col] = *(const float4*)&TT[w][rr][li*8 + h2*4]; \
    }}                                                                  \
  __builtin_amdgcn_sched_barrier(0); }

__global__ __launch_bounds__(256) void k_score(
    const ushort_t* __restrict__ Eh, const ushort_t* __restrict__ El,
    const float* __restrict__ T, float* __restrict__ out){
  __shared__ short8 TB[32][64];     // 32 KB: frag-ordered T tile (hi/lo)
  __shared__ float TT[4][16][132];  // 33 KB: per-wave transpose tiles
  const int t = threadIdx.x, lane = t & 63, w = t >> 6;  // 4 waves
  const int li = lane & 15, g = lane >> 4;
  const int i0 = blockIdx.x * 128;

  // ---- stage T tile (128 rows) into LDS fragment order, hi/lo bf16 ----
#pragma unroll
  for (int i = 0; i < 8; ++i){
    int e4 = t + 256 * i;            // [128 rows][16 float4-cols]
    int r = e4 >> 4, c4 = e4 & 15;
    int gi = i0 + r;
    float4 v = make_float4(0.f, 0.f, 0.f, 0.f);
    if (gi < NITEMS) v = ((const float4*)(T + (size_t)gi * 64))[c4];
    int nt = r >> 4, li2 = r & 15;
    int kc = c4 >> 3, g2 = (c4 >> 1) & 3, j0 = (c4 & 1) * 4;
    float f[4] = {v.x, v.y, v.z, v.w};
    u64_t ph = 0, pl = 0;
#pragma unroll
    for (int j = 0; j < 4; ++j){
      ushort_t hh = f2b(f[j]);
      ushort_t ll = f2b(f[j] - b2f(hh));
      ph |= (u64_t)hh << (16*j);
      pl |= (u64_t)ll << (16*j);
    }
    *(u64_t*)((ushort_t*)&TB[nt*2 + kc][g2*16 + li2] + j0) = ph;
    *(u64_t*)((ushort_t*)&TB[16 + nt*2 + kc][g2*16 + li2] + j0) = pl;
  }
  __syncthreads();

  // ---- 8 batch chunks, A double-buffered ----
  short8 Ah0[2], Al0[2], Ah1[2], Al1[2];
  LOADA(Ah0, Al0, 0);
  CHUNK(0, Ah0, Al0, Ah1, Al1, 1)
  CHUNK(1, Ah1, Al1, Ah0, Al0, 1)
  CHUNK(2, Ah0, Al0, Ah1, Al1, 1)
  CHUNK(3, Ah1, Al1, Ah0, Al0, 1)
  CHUNK(4, Ah0, Al0, Ah1, Al1, 1)
  CHUNK(5, Ah1, Al1, Ah0, Al0, 1)
  CHUNK(6, Ah0, Al0, Ah1, Al1, 1)
  CHUNK(7, Ah1, Al1, Ah0, Al0, 0)
}

// ----------------------------------------------------------------- launch --
extern "C" void kernel_launch(void* const* d_in, const int* in_sizes, int n_in,
                              void* d_out, int out_size, void* d_ws, size_t ws_size,
                              hipStream_t stream){
  const int*   ids      = (const int*)  d_in[0];
  const float* item_emb = (const float*)d_in[1];
  const float* pos_emb  = (const float*)d_in[2];
  const float* ln1g     = (const float*)d_in[3];
  const float* ln1b     = (const float*)d_in[4];
  const float* Wq       = (const float*)d_in[5];
  const float* bq       = (const float*)d_in[6];
  const float* Wk       = (const float*)d_in[7];
  const float* bk       = (const float*)d_in[8];
  const float* Wv       = (const float*)d_in[9];
  const float* bv       = (const float*)d_in[10];
  const float* ln2g     = (const float*)d_in[11];
  const float* ln2b     = (const float*)d_in[12];
  const float* W1       = (const float*)d_in[13];
  const float* b1       = (const float*)d_in[14];
  const float* W2       = (const float*)d_in[15];
  const float* b2       = (const float*)d_in[16];
  const float* lnfg     = (const float*)d_in[17];
  const float* lnfb     = (const float*)d_in[18];
  const float* items    = (const float*)d_in[19];
  float* out = (float*)d_out;

  ushort_t* Ehp = (ushort_t*)d_ws;          // 64 KB
  ushort_t* Elp = Ehp + 512 * 64;           // 64 KB

  k_layers<<<Bsz, 1024, 0, stream>>>(ids, item_emb, pos_emb,
      ln1g, ln1b, Wq, bq, Wk, bk, Wv, bv,
      ln2g, ln2b, W1, b1, W2, b2, lnfg, lnfb, Ehp, Elp);
  k_score<<<1563, 256, 0, stream>>>(Ehp, Elp, items, out);
}

// Round 14
// 189.721 us; speedup vs baseline: 1.5884x; 1.0502x over previous
//
#include <hip/hip_runtime.h>
#include <cstddef>

// SASRec inference. Round 14: k_layers occupancy fix — 512-thread blocks
// (8 waves), 4 f32 LDS buffers (68 KB) via register-snapshot reuse, ballot
// mask, __launch_bounds__(512,4) -> 2 blocks/CU, 1 grid round (was 2).
// Math bit-identical. k_score = exact R9 (best), single launch.

#define NITEMS 200000
#define Bsz 512
#define Ssz 64
#define Dsz 64
#define EPSV 1e-3f
#define NEGV (-4294967295.0f)   // -2^32 + 1

typedef __attribute__((ext_vector_type(8))) short short8;   // 8 bf16
typedef __attribute__((ext_vector_type(4))) float f32x4;
typedef unsigned short ushort_t;
typedef unsigned long long u64_t;

static __device__ __forceinline__ float wsum(float v){
#pragma unroll
  for (int o = 32; o > 0; o >>= 1) v += __shfl_xor(v, o, 64);
  return v;
}
static __device__ __forceinline__ float wmax(float v){
#pragma unroll
  for (int o = 32; o > 0; o >>= 1) v = fmaxf(v, __shfl_xor(v, o, 64));
  return v;
}

// bf16 round-to-nearest-even (finite inputs only)
static __device__ __forceinline__ ushort_t f2b(float f){
  unsigned u = __float_as_uint(f);
  unsigned r = u + 0x7fffu + ((u >> 16) & 1u);
  return (ushort_t)(r >> 16);
}
static __device__ __forceinline__ float b2f(ushort_t h){
  return __uint_as_float(((unsigned)h) << 16);
}

// 8 consecutive f32 -> bf16 hi/lo fragments (in registers)
static __device__ __forceinline__ void a_frag(const float* __restrict__ p,
    short8& h8, short8& l8){
  float4 v0 = *(const float4*)p, v1 = *(const float4*)(p + 4);
  float f[8] = {v0.x,v0.y,v0.z,v0.w,v1.x,v1.y,v1.z,v1.w};
#pragma unroll
  for (int j = 0; j < 8; ++j){
    ushort_t hh = f2b(f[j]);
    h8[j] = (short)hh;
    l8[j] = (short)f2b(f[j] - b2f(hh));
  }
}

// 2-tile GEMM strip vs weight from global: A-frags in registers.
// acc[nt] for cols cbh*32 + nt*16 + li, rows qb*16 + g*4 + r4.
static __device__ __forceinline__ void mmW2r(const short8 ah[2], const short8 al[2],
    const float* __restrict__ Wg, int cbh, int li, int g, f32x4 acc[2]){
#pragma unroll
  for (int nt = 0; nt < 2; ++nt){
    acc[nt] = (f32x4)(0.f);
#pragma unroll
    for (int kc = 0; kc < 2; ++kc){
      float f[8];
#pragma unroll
      for (int j = 0; j < 8; ++j)
        f[j] = Wg[(kc*32 + g*8 + j)*64 + cbh*32 + nt*16 + li];
      short8 bh, bl;
#pragma unroll
      for (int j = 0; j < 8; ++j){
        ushort_t hh = f2b(f[j]);
        bh[j] = (short)hh;
        bl[j] = (short)f2b(f[j] - b2f(hh));
      }
      acc[nt] = __builtin_amdgcn_mfma_f32_16x16x32_bf16(ah[kc], bh, acc[nt], 0, 0, 0);
      acc[nt] = __builtin_amdgcn_mfma_f32_16x16x32_bf16(ah[kc], bl, acc[nt], 0, 0, 0);
      acc[nt] = __builtin_amdgcn_mfma_f32_16x16x32_bf16(al[kc], bh, acc[nt], 0, 0, 0);
    }
  }
}

// 2-tile GEMM strip: A-frags in registers, B rows from f32 LDS ([n][k] layout)
static __device__ __forceinline__ void mmB2(const short8 ah[2], const short8 al[2],
    const float (*__restrict__ B)[68], int cbh, int li, int g, f32x4 acc[2]){
#pragma unroll
  for (int nt = 0; nt < 2; ++nt){
    acc[nt] = (f32x4)(0.f);
#pragma unroll
    for (int kc = 0; kc < 2; ++kc){
      short8 bh, bl;
      a_frag(&B[cbh*32 + nt*16 + li][kc*32 + g*8], bh, bl);
      acc[nt] = __builtin_amdgcn_mfma_f32_16x16x32_bf16(ah[kc], bh, acc[nt], 0, 0, 0);
      acc[nt] = __builtin_amdgcn_mfma_f32_16x16x32_bf16(ah[kc], bl, acc[nt], 0, 0, 0);
      acc[nt] = __builtin_amdgcn_mfma_f32_16x16x32_bf16(al[kc], bh, acc[nt], 0, 0, 0);
    }
  }
}

// ------------------------------------------------------ fused block layers --
__global__ __launch_bounds__(512, 4) void k_layers(const int* __restrict__ ids,
    const float* __restrict__ item_emb, const float* __restrict__ pos_emb,
    const float* __restrict__ ln1g, const float* __restrict__ ln1b,
    const float* __restrict__ Wq, const float* __restrict__ bq,
    const float* __restrict__ Wk, const float* __restrict__ bk,
    const float* __restrict__ Wv, const float* __restrict__ bv,
    const float* __restrict__ ln2g, const float* __restrict__ ln2b,
    const float* __restrict__ W1, const float* __restrict__ b1,
    const float* __restrict__ W2, const float* __restrict__ b2,
    const float* __restrict__ lnfg, const float* __restrict__ lnfb,
    ushort_t* __restrict__ Eh, ushort_t* __restrict__ El){
  __shared__ float B0[64][68];   // seq -> V^T -> (next) seq
  __shared__ float B1[64][68];   // xq (LN1 out) -> res (LN2 out)
  __shared__ float B2[64][68];   // Q -> scores/P -> FFN hidden
  __shared__ float B3[64][68];   // K -> x (attn+residual)

  const int t = threadIdx.x;
  const int lane = t & 63, wid = t >> 6;        // 8 waves
  const int li = lane & 15, g = lane >> 4;
  const int qb = wid & 3, cbh = wid >> 2;       // rows qb*16.., cols cbh*32..+31
  const int b = blockIdx.x;

  // ---- phase 0 (fused embed): gather + pos -> B0 (f32); ballot mask ----
#pragma unroll
  for (int it = 0; it < 2; ++it){
    int e4 = t + 512 * it;
    int r = e4 >> 4, c4 = e4 & 15, c = c4 * 4;
    int id = ids[b * Ssz + r];
    float4 v = make_float4(0.f, 0.f, 0.f, 0.f);
    if (id != NITEMS){
      float4 a = ((const float4*)(item_emb + (size_t)id * 64))[c4];
      float4 p = ((const float4*)(pos_emb + r * 64))[c4];
      v = make_float4(a.x + p.x, a.y + p.y, a.z + p.z, a.w + p.w);
    }
    *(float4*)&B0[r][c] = v;
  }
  const int myid = ids[b * Ssz + lane];
  const u64_t mvec = __ballot(myid != NITEMS);   // bit r = row r valid

  for (int l = 0; l < 2; ++l){
    __syncthreads();   // fences phase-0 (l=0) / previous layer-out (l=1)

    // ---- LN1: B0 -> B1 (8 rows/wave) ----
    for (int r = wid; r < 64; r += 8){
      float x = B0[r][lane];
      float mu = wsum(x) * (1.f / 64.f);
      float dv = x - mu;
      float var = wsum(dv * dv) * (1.f / 64.f);
      B1[r][lane] = dv * (1.f / sqrtf(var + EPSV)) * ln1g[l*64 + lane] + ln1b[l*64 + lane];
    }
    __syncthreads();

    // ---- ph1: A-frags of seq (B0) and LN1 (B1); Q -> B2, K -> B3 ----
    short8 a0h[2], a0l[2], a1h[2], a1l[2];
#pragma unroll
    for (int kc = 0; kc < 2; ++kc){
      a_frag(&B0[qb*16 + li][kc*32 + g*8], a0h[kc], a0l[kc]);
      a_frag(&B1[qb*16 + li][kc*32 + g*8], a1h[kc], a1l[kc]);
    }
    { f32x4 acc[2]; mmW2r(a1h, a1l, Wq + l*4096, cbh, li, g, acc);
#pragma unroll
      for (int nt = 0; nt < 2; ++nt){
        int col = cbh*32 + nt*16 + li; float bb = bq[l*64 + col];
#pragma unroll
        for (int r4 = 0; r4 < 4; ++r4) B2[qb*16 + g*4 + r4][col] = acc[nt][r4] + bb;
      }
    }
    { f32x4 acc[2]; mmW2r(a0h, a0l, Wk + l*4096, cbh, li, g, acc);
#pragma unroll
      for (int nt = 0; nt < 2; ++nt){
        int col = cbh*32 + nt*16 + li; float bb = bk[l*64 + col];
#pragma unroll
        for (int r4 = 0; r4 < 4; ++r4) B3[qb*16 + g*4 + r4][col] = acc[nt][r4] + bb;
      }
    }
    __syncthreads();

    // ---- ph2: V (from seq frags) -> B0 transposed; snapshot Q frags ----
    { f32x4 acc[2]; mmW2r(a0h, a0l, Wv + l*4096, cbh, li, g, acc);
#pragma unroll
      for (int nt = 0; nt < 2; ++nt){
        int col = cbh*32 + nt*16 + li; float bb = bv[l*64 + col];
#pragma unroll
        for (int r4 = 0; r4 < 4; ++r4) B0[col][qb*16 + g*4 + r4] = acc[nt][r4] + bb;
      }
    }
    short8 qh[2], ql[2];
#pragma unroll
    for (int kc = 0; kc < 2; ++kc)
      a_frag(&B2[qb*16 + li][kc*32 + g*8], qh[kc], ql[kc]);
    __syncthreads();

    // ---- ph3: scores = Q @ K^T -> B2 (Q dead, snapshotted) ----
    { f32x4 acc[2]; mmB2(qh, ql, B3, cbh, li, g, acc);
#pragma unroll
      for (int nt = 0; nt < 2; ++nt){
        int col = cbh*32 + nt*16 + li;
#pragma unroll
        for (int r4 = 0; r4 < 4; ++r4) B2[qb*16 + g*4 + r4][col] = acc[nt][r4];
      }
    }
    __syncthreads();

    // ---- ph4: masked softmax in place (B2) ----
    for (int r = wid; r < 64; r += 8){
      float raw = B2[r][lane];
      bool valid = (lane <= r) && ((mvec >> lane) & 1);
      float sc = valid ? raw * 0.125f : NEGV;
      float m = wmax(sc);
      float e = __expf(sc - m);
      float ssumv = wsum(e);
      float qm = ((mvec >> r) & 1) ? 1.f : 0.f;
      B2[r][lane] = (e / ssumv) * qm;
    }
    __syncthreads();

    // ---- ph5: x = P @ V + xq -> B3 (K dead) ----
    { short8 pfh[2], pfl[2];
#pragma unroll
      for (int kc = 0; kc < 2; ++kc)
        a_frag(&B2[qb*16 + li][kc*32 + g*8], pfh[kc], pfl[kc]);
      f32x4 acc[2]; mmB2(pfh, pfl, B0, cbh, li, g, acc);
#pragma unroll
      for (int nt = 0; nt < 2; ++nt){
        int col = cbh*32 + nt*16 + li;
#pragma unroll
        for (int r4 = 0; r4 < 4; ++r4){
          int row = qb*16 + g*4 + r4;
          B3[row][col] = acc[nt][r4] + B1[row][col];
        }
      }
    }
    __syncthreads();

    // ---- ph6: LN2: B3 -> B1 (xq dead) ----
    for (int r = wid; r < 64; r += 8){
      float x = B3[r][lane];
      float mu = wsum(x) * (1.f / 64.f);
      float dv = x - mu;
      float var = wsum(dv * dv) * (1.f / 64.f);
      B1[r][lane] = dv * (1.f / sqrtf(var + EPSV)) * ln2g[l*64 + lane] + ln2b[l*64 + lane];
    }
    __syncthreads();

    // ---- ph7: h = relu(res @ W1 + b1) -> B2 (P dead) ----
    { short8 rh[2], rl[2];
#pragma unroll
      for (int kc = 0; kc < 2; ++kc)
        a_frag(&B1[qb*16 + li][kc*32 + g*8], rh[kc], rl[kc]);
      f32x4 acc[2]; mmW2r(rh, rl, W1 + l*4096, cbh, li, g, acc);
#pragma unroll
      for (int nt = 0; nt < 2; ++nt){
        int col = cbh*32 + nt*16 + li; float bb = b1[l*64 + col];
#pragma unroll
        for (int r4 = 0; r4 < 4; ++r4)
          B2[qb*16 + g*4 + r4][col] = fmaxf(acc[nt][r4] + bb, 0.f);
      }
    }
    __syncthreads();

    // ---- ph8: out = (h @ W2 + b2 + res) * mask -> B0 (V^T dead) ----
    { short8 hh[2], hl[2];
#pragma unroll
      for (int kc = 0; kc < 2; ++kc)
        a_frag(&B2[qb*16 + li][kc*32 + g*8], hh[kc], hl[kc]);
      f32x4 acc[2]; mmW2r(hh, hl, W2 + l*4096, cbh, li, g, acc);
#pragma unroll
      for (int nt = 0; nt < 2; ++nt){
        int col = cbh*32 + nt*16 + li; float bb = b2[l*64 + col];
#pragma unroll
        for (int r4 = 0; r4 < 4; ++r4){
          int row = qb*16 + g*4 + r4;
          float m = ((mvec >> row) & 1) ? 1.f : 0.f;
          B0[row][col] = (acc[nt][r4] + bb + B1[row][col]) * m;
        }
      }
    }
  }

  // ---- fused final LN on row 63 -> packed bf16 hi/lo E ----
  __syncthreads();
  if (wid == 0){
    float x = B0[63][lane];
    float mu = wsum(x) * (1.f / 64.f);
    float dv = x - mu;
    float var = wsum(dv * dv) * (1.f / 64.f);
    float o = dv * (1.f / sqrtf(var + EPSV)) * lnfg[lane] + lnfb[lane];
    ushort_t h = f2b(o);
    Eh[b * 64 + lane] = h;
    El[b * 64 + lane] = f2b(o - b2f(h));
  }
}

// --------------------------------------------------------------- scoring ---
// Exact R9 kernel (best config), single launch.
#define LOADA(DH, DL, c) { int er = (c)*64 + w*16 + li;                 \
  DH[0] = *(const short8*)&Eh[er*64 + g*8];                             \
  DH[1] = *(const short8*)&Eh[er*64 + 32 + g*8];                        \
  DL[0] = *(const short8*)&El[er*64 + g*8];                             \
  DL[1] = *(const short8*)&El[er*64 + 32 + g*8]; }

#define CHUNK(c, CAh, CAl, NAh, NAl, PF) {                              \
  if (PF) LOADA(NAh, NAl, (c)+1);                                       \
  f32x4 acc[8];                                                         \
  _Pragma("unroll") for (int nt = 0; nt < 8; ++nt) acc[nt] = (f32x4)(0.f); \
  _Pragma("unroll") for (int kc = 0; kc < 2; ++kc){                     \
    _Pragma("unroll") for (int nt = 0; nt < 8; ++nt){                   \
      short8 bh = TB[nt*2 + kc][lane];                                  \
      short8 bl = TB[16 + nt*2 + kc][lane];                             \
      acc[nt] = __builtin_amdgcn_mfma_f32_16x16x32_bf16(CAh[kc], bh, acc[nt], 0, 0, 0); \
      acc[nt] = __builtin_amdgcn_mfma_f32_16x16x32_bf16(CAh[kc], bl, acc[nt], 0, 0, 0); \
      acc[nt] = __builtin_amdgcn_mfma_f32_16x16x32_bf16(CAl[kc], bh, acc[nt], 0, 0, 0); \
    }}                                                                  \
  _Pragma("unroll") for (int nt = 0; nt < 8; ++nt)                      \
    _Pragma("unroll") for (int r = 0; r < 4; ++r)                       \
      TT[w][g*4 + r][nt*16 + li] = acc[nt][r];                          \
  asm volatile("s_waitcnt lgkmcnt(0)" ::: "memory");                    \
  __builtin_amdgcn_sched_barrier(0);                                    \
  _Pragma("unroll") for (int k = 0; k < 4; ++k){                        \
    int rr = 4*k + g;                                                   \
    size_t rb = (size_t)((c)*64 + w*16 + rr) * NITEMS;                  \
    _Pragma("unroll") for (int h2 = 0; h2 < 2; ++h2){                   \
      int col = i0 + li*8 + h2*4;                                       \
      if (col < NITEMS)                                                 \
        *(float4*)&out[rb + col] = *(const float4*)&TT[w][rr][li*8 + h2*4]; \
    }}                                                                  \
  __builtin_amdgcn_sched_barrier(0); }

__global__ __launch_bounds__(256) void k_score(
    const ushort_t* __restrict__ Eh, const ushort_t* __restrict__ El,
    const float* __restrict__ T, float* __restrict__ out){
  __shared__ short8 TB[32][64];     // 32 KB: frag-ordered T tile (hi/lo)
  __shared__ float TT[4][16][132];  // 33 KB: per-wave transpose tiles
  const int t = threadIdx.x, lane = t & 63, w = t >> 6;  // 4 waves
  const int li = lane & 15, g = lane >> 4;
  const int i0 = blockIdx.x * 128;

  // ---- stage T tile (128 rows) into LDS fragment order, hi/lo bf16 ----
#pragma unroll
  for (int i = 0; i < 8; ++i){
    int e4 = t + 256 * i;            // [128 rows][16 float4-cols]
    int r = e4 >> 4, c4 = e4 & 15;
    int gi = i0 + r;
    float4 v = make_float4(0.f, 0.f, 0.f, 0.f);
    if (gi < NITEMS) v = ((const float4*)(T + (size_t)gi * 64))[c4];
    int nt = r >> 4, li2 = r & 15;
    int kc = c4 >> 3, g2 = (c4 >> 1) & 3, j0 = (c4 & 1) * 4;
    float f[4] = {v.x, v.y, v.z, v.w};
    u64_t ph = 0, pl = 0;
#pragma unroll
    for (int j = 0; j < 4; ++j){
      ushort_t hh = f2b(f[j]);
      ushort_t ll = f2b(f[j] - b2f(hh));
      ph |= (u64_t)hh << (16*j);
      pl |= (u64_t)ll << (16*j);
    }
    *(u64_t*)((ushort_t*)&TB[nt*2 + kc][g2*16 + li2] + j0) = ph;
    *(u64_t*)((ushort_t*)&TB[16 + nt*2 + kc][g2*16 + li2] + j0) = pl;
  }
  __syncthreads();

  // ---- 8 batch chunks, A double-buffered ----
  short8 Ah0[2], Al0[2], Ah1[2], Al1[2];
  LOADA(Ah0, Al0, 0);
  CHUNK(0, Ah0, Al0, Ah1, Al1, 1)
  CHUNK(1, Ah1, Al1, Ah0, Al0, 1)
  CHUNK(2, Ah0, Al0, Ah1, Al1, 1)
  CHUNK(3, Ah1, Al1, Ah0, Al0, 1)
  CHUNK(4, Ah0, Al0, Ah1, Al1, 1)
  CHUNK(5, Ah1, Al1, Ah0, Al0, 1)
  CHUNK(6, Ah0, Al0, Ah1, Al1, 1)
  CHUNK(7, Ah1, Al1, Ah0, Al0, 0)
}

// ----------------------------------------------------------------- launch --
extern "C" void kernel_launch(void* const* d_in, const int* in_sizes, int n_in,
                              void* d_out, int out_size, void* d_ws, size_t ws_size,
                              hipStream_t stream){
  const int*   ids      = (const int*)  d_in[0];
  const float* item_emb = (const float*)d_in[1];
  const float* pos_emb  = (const float*)d_in[2];
  const float* ln1g     = (const float*)d_in[3];
  const float* ln1b     = (const float*)d_in[4];
  const float* Wq       = (const float*)d_in[5];
  const float* bq       = (const float*)d_in[6];
  const float* Wk       = (const float*)d_in[7];
  const float* bk       = (const float*)d_in[8];
  const float* Wv       = (const float*)d_in[9];
  const float* bv       = (const float*)d_in[10];
  const float* ln2g     = (const float*)d_in[11];
  const float* ln2b     = (const float*)d_in[12];
  const float* W1       = (const float*)d_in[13];
  const float* b1       = (const float*)d_in[14];
  const float* W2       = (const float*)d_in[15];
  const float* b2       = (const float*)d_in[16];
  const float* lnfg     = (const float*)d_in[17];
  const float* lnfb     = (const float*)d_in[18];
  const float* items    = (const float*)d_in[19];
  float* out = (float*)d_out;

  ushort_t* Ehp = (ushort_t*)d_ws;          // 64 KB
  ushort_t* Elp = Ehp + 512 * 64;           // 64 KB

  k_layers<<<Bsz, 512, 0, stream>>>(ids, item_emb, pos_emb,
      ln1g, ln1b, Wq, bq, Wk, bk, Wv, bv,
      ln2g, ln2b, W1, b1, W2, b2, lnfg, lnfb, Ehp, Elp);
  k_score<<<1563, 256, 0, stream>>>(Ehp, Elp, items, out);
}

// Round 15
// 178.269 us; speedup vs baseline: 1.6904x; 1.0642x over previous
//
#include <hip/hip_runtime.h>
#include <cstddef>

// SASRec inference. Round 15: weight pre-packing — k_packw converts all 10
// 64x64 weights ONCE into MFMA-fragment-ordered bf16 hi/lo (160 KB, L2-hot).
// k_layers' per-phase weight path becomes 8 coalesced 16B loads + MFMA (no
// scalar gathers, no conversion VALU, ~40 fewer live VGPRs -> no spills at
// the 128-reg cap). Math bit-identical. k_score = exact R9.

#define NITEMS 200000
#define Bsz 512
#define Ssz 64
#define Dsz 64
#define EPSV 1e-3f
#define NEGV (-4294967295.0f)   // -2^32 + 1

typedef __attribute__((ext_vector_type(8))) short short8;   // 8 bf16
typedef __attribute__((ext_vector_type(4))) float f32x4;
typedef unsigned short ushort_t;
typedef unsigned long long u64_t;

static __device__ __forceinline__ float wsum(float v){
#pragma unroll
  for (int o = 32; o > 0; o >>= 1) v += __shfl_xor(v, o, 64);
  return v;
}
static __device__ __forceinline__ float wmax(float v){
#pragma unroll
  for (int o = 32; o > 0; o >>= 1) v = fmaxf(v, __shfl_xor(v, o, 64));
  return v;
}

// bf16 round-to-nearest-even (finite inputs only)
static __device__ __forceinline__ ushort_t f2b(float f){
  unsigned u = __float_as_uint(f);
  unsigned r = u + 0x7fffu + ((u >> 16) & 1u);
  return (ushort_t)(r >> 16);
}
static __device__ __forceinline__ float b2f(ushort_t h){
  return __uint_as_float(((unsigned)h) << 16);
}

// 8 consecutive f32 -> bf16 hi/lo fragments (in registers)
static __device__ __forceinline__ void a_frag(const float* __restrict__ p,
    short8& h8, short8& l8){
  float4 v0 = *(const float4*)p, v1 = *(const float4*)(p + 4);
  float f[8] = {v0.x,v0.y,v0.z,v0.w,v1.x,v1.y,v1.z,v1.w};
#pragma unroll
  for (int j = 0; j < 8; ++j){
    ushort_t hh = f2b(f[j]);
    h8[j] = (short)hh;
    l8[j] = (short)f2b(f[j] - b2f(hh));
  }
}

// ----------------------------------------------------------- weight pack ----
// Wp layout: weight m (= layer*5 + which), slot s = cb*2+kc (cb: 16-col blk),
// hi at [m*16+s][lane], lo at [m*16+8+s][lane]; value[j] = W[kc*32+g*8+j][cb*16+li]
__global__ __launch_bounds__(512) void k_packw(const float* __restrict__ Wq,
    const float* __restrict__ Wk, const float* __restrict__ Wv,
    const float* __restrict__ W1, const float* __restrict__ W2,
    short8* __restrict__ Wp){
  const int m = blockIdx.x;            // 0..9
  const int l = m / 5, which = m % 5;
  const float* Ws[5] = {Wq, Wk, Wv, W1, W2};
  const float* Wg = Ws[which] + l * 4096;
  const int t = threadIdx.x;
  const int lane = t & 63, s = t >> 6;           // s = 0..7
  const int li = lane & 15, g = lane >> 4;
  const int cb = s >> 1, kc = s & 1;
  short8 h, lo;
#pragma unroll
  for (int j = 0; j < 8; ++j){
    float f = Wg[(kc*32 + g*8 + j)*64 + cb*16 + li];
    ushort_t hh = f2b(f);
    h[j] = (short)hh;
    lo[j] = (short)f2b(f - b2f(hh));
  }
  Wp[(m*16 + s)*64 + lane] = h;
  Wp[(m*16 + 8 + s)*64 + lane] = lo;
}

// 2-tile GEMM strip vs PACKED weight frags (8 coalesced 16B loads + MFMA)
static __device__ __forceinline__ void mmW2p(const short8 ah[2], const short8 al[2],
    const short8* __restrict__ Wp, int m, int cbh, int lane, f32x4 acc[2]){
#pragma unroll
  for (int nt = 0; nt < 2; ++nt){
    acc[nt] = (f32x4)(0.f);
#pragma unroll
    for (int kc = 0; kc < 2; ++kc){
      int s = (cbh*2 + nt)*2 + kc;
      short8 bh = Wp[(m*16 + s)*64 + lane];
      short8 bl = Wp[(m*16 + 8 + s)*64 + lane];
      acc[nt] = __builtin_amdgcn_mfma_f32_16x16x32_bf16(ah[kc], bh, acc[nt], 0, 0, 0);
      acc[nt] = __builtin_amdgcn_mfma_f32_16x16x32_bf16(ah[kc], bl, acc[nt], 0, 0, 0);
      acc[nt] = __builtin_amdgcn_mfma_f32_16x16x32_bf16(al[kc], bh, acc[nt], 0, 0, 0);
    }
  }
}

// 2-tile GEMM strip: A-frags in registers, B rows from f32 LDS ([n][k] layout)
static __device__ __forceinline__ void mmB2(const short8 ah[2], const short8 al[2],
    const float (*__restrict__ B)[68], int cbh, int li, int g, f32x4 acc[2]){
#pragma unroll
  for (int nt = 0; nt < 2; ++nt){
    acc[nt] = (f32x4)(0.f);
#pragma unroll
    for (int kc = 0; kc < 2; ++kc){
      short8 bh, bl;
      a_frag(&B[cbh*32 + nt*16 + li][kc*32 + g*8], bh, bl);
      acc[nt] = __builtin_amdgcn_mfma_f32_16x16x32_bf16(ah[kc], bh, acc[nt], 0, 0, 0);
      acc[nt] = __builtin_amdgcn_mfma_f32_16x16x32_bf16(ah[kc], bl, acc[nt], 0, 0, 0);
      acc[nt] = __builtin_amdgcn_mfma_f32_16x16x32_bf16(al[kc], bh, acc[nt], 0, 0, 0);
    }
  }
}

// ------------------------------------------------------ fused block layers --
__global__ __launch_bounds__(512, 4) void k_layers(const int* __restrict__ ids,
    const float* __restrict__ item_emb, const float* __restrict__ pos_emb,
    const float* __restrict__ ln1g, const float* __restrict__ ln1b,
    const short8* __restrict__ Wp,
    const float* __restrict__ bq, const float* __restrict__ bk,
    const float* __restrict__ bv,
    const float* __restrict__ ln2g, const float* __restrict__ ln2b,
    const float* __restrict__ b1, const float* __restrict__ b2,
    const float* __restrict__ lnfg, const float* __restrict__ lnfb,
    ushort_t* __restrict__ Eh, ushort_t* __restrict__ El){
  __shared__ float B0[64][68];   // seq -> V^T -> (next) seq
  __shared__ float B1[64][68];   // xq (LN1 out) -> res (LN2 out)
  __shared__ float B2[64][68];   // Q -> scores/P -> FFN hidden
  __shared__ float B3[64][68];   // K -> x (attn+residual)

  const int t = threadIdx.x;
  const int lane = t & 63, wid = t >> 6;        // 8 waves
  const int li = lane & 15, g = lane >> 4;
  const int qb = wid & 3, cbh = wid >> 2;       // rows qb*16.., cols cbh*32..+31
  const int b = blockIdx.x;

  // ---- phase 0 (fused embed): gather + pos -> B0 (f32); ballot mask ----
#pragma unroll
  for (int it = 0; it < 2; ++it){
    int e4 = t + 512 * it;
    int r = e4 >> 4, c4 = e4 & 15, c = c4 * 4;
    int id = ids[b * Ssz + r];
    float4 v = make_float4(0.f, 0.f, 0.f, 0.f);
    if (id != NITEMS){
      float4 a = ((const float4*)(item_emb + (size_t)id * 64))[c4];
      float4 p = ((const float4*)(pos_emb + r * 64))[c4];
      v = make_float4(a.x + p.x, a.y + p.y, a.z + p.z, a.w + p.w);
    }
    *(float4*)&B0[r][c] = v;
  }
  const int myid = ids[b * Ssz + lane];
  const u64_t mvec = __ballot(myid != NITEMS);   // bit r = row r valid

  for (int l = 0; l < 2; ++l){
    const int mb = l * 5;
    __syncthreads();   // fences phase-0 (l=0) / previous layer-out (l=1)

    // ---- LN1: B0 -> B1 (8 rows/wave) ----
    for (int r = wid; r < 64; r += 8){
      float x = B0[r][lane];
      float mu = wsum(x) * (1.f / 64.f);
      float dv = x - mu;
      float var = wsum(dv * dv) * (1.f / 64.f);
      B1[r][lane] = dv * (1.f / sqrtf(var + EPSV)) * ln1g[l*64 + lane] + ln1b[l*64 + lane];
    }
    __syncthreads();

    // ---- ph1: A-frags of seq (B0) and LN1 (B1); Q -> B2, K -> B3 ----
    short8 a0h[2], a0l[2], a1h[2], a1l[2];
#pragma unroll
    for (int kc = 0; kc < 2; ++kc){
      a_frag(&B0[qb*16 + li][kc*32 + g*8], a0h[kc], a0l[kc]);
      a_frag(&B1[qb*16 + li][kc*32 + g*8], a1h[kc], a1l[kc]);
    }
    { f32x4 acc[2]; mmW2p(a1h, a1l, Wp, mb + 0, cbh, lane, acc);
#pragma unroll
      for (int nt = 0; nt < 2; ++nt){
        int col = cbh*32 + nt*16 + li; float bb = bq[l*64 + col];
#pragma unroll
        for (int r4 = 0; r4 < 4; ++r4) B2[qb*16 + g*4 + r4][col] = acc[nt][r4] + bb;
      }
    }
    { f32x4 acc[2]; mmW2p(a0h, a0l, Wp, mb + 1, cbh, lane, acc);
#pragma unroll
      for (int nt = 0; nt < 2; ++nt){
        int col = cbh*32 + nt*16 + li; float bb = bk[l*64 + col];
#pragma unroll
        for (int r4 = 0; r4 < 4; ++r4) B3[qb*16 + g*4 + r4][col] = acc[nt][r4] + bb;
      }
    }
    __syncthreads();

    // ---- ph2: V (from seq frags) -> B0 transposed; snapshot Q frags ----
    { f32x4 acc[2]; mmW2p(a0h, a0l, Wp, mb + 2, cbh, lane, acc);
#pragma unroll
      for (int nt = 0; nt < 2; ++nt){
        int col = cbh*32 + nt*16 + li; float bb = bv[l*64 + col];
#pragma unroll
        for (int r4 = 0; r4 < 4; ++r4) B0[col][qb*16 + g*4 + r4] = acc[nt][r4] + bb;
      }
    }
    short8 qh[2], ql[2];
#pragma unroll
    for (int kc = 0; kc < 2; ++kc)
      a_frag(&B2[qb*16 + li][kc*32 + g*8], qh[kc], ql[kc]);
    __syncthreads();

    // ---- ph3: scores = Q @ K^T -> B2 (Q dead, snapshotted) ----
    { f32x4 acc[2]; mmB2(qh, ql, B3, cbh, li, g, acc);
#pragma unroll
      for (int nt = 0; nt < 2; ++nt){
        int col = cbh*32 + nt*16 + li;
#pragma unroll
        for (int r4 = 0; r4 < 4; ++r4) B2[qb*16 + g*4 + r4][col] = acc[nt][r4];
      }
    }
    __syncthreads();

    // ---- ph4: masked softmax in place (B2) ----
    for (int r = wid; r < 64; r += 8){
      float raw = B2[r][lane];
      bool valid = (lane <= r) && ((mvec >> lane) & 1);
      float sc = valid ? raw * 0.125f : NEGV;
      float m = wmax(sc);
      float e = __expf(sc - m);
      float ssumv = wsum(e);
      float qm = ((mvec >> r) & 1) ? 1.f : 0.f;
      B2[r][lane] = (e / ssumv) * qm;
    }
    __syncthreads();

    // ---- ph5: x = P @ V + xq -> B3 (K dead) ----
    { short8 pfh[2], pfl[2];
#pragma unroll
      for (int kc = 0; kc < 2; ++kc)
        a_frag(&B2[qb*16 + li][kc*32 + g*8], pfh[kc], pfl[kc]);
      f32x4 acc[2]; mmB2(pfh, pfl, B0, cbh, li, g, acc);
#pragma unroll
      for (int nt = 0; nt < 2; ++nt){
        int col = cbh*32 + nt*16 + li;
#pragma unroll
        for (int r4 = 0; r4 < 4; ++r4){
          int row = qb*16 + g*4 + r4;
          B3[row][col] = acc[nt][r4] + B1[row][col];
        }
      }
    }
    __syncthreads();

    // ---- ph6: LN2: B3 -> B1 (xq dead) ----
    for (int r = wid; r < 64; r += 8){
      float x = B3[r][lane];
      float mu = wsum(x) * (1.f / 64.f);
      float dv = x - mu;
      float var = wsum(dv * dv) * (1.f / 64.f);
      B1[r][lane] = dv * (1.f / sqrtf(var + EPSV)) * ln2g[l*64 + lane] + ln2b[l*64 + lane];
    }
    __syncthreads();

    // ---- ph7: h = relu(res @ W1 + b1) -> B2 (P dead) ----
    { short8 rh[2], rl[2];
#pragma unroll
      for (int kc = 0; kc < 2; ++kc)
        a_frag(&B1[qb*16 + li][kc*32 + g*8], rh[kc], rl[kc]);
      f32x4 acc[2]; mmW2p(rh, rl, Wp, mb + 3, cbh, lane, acc);
#pragma unroll
      for (int nt = 0; nt < 2; ++nt){
        int col = cbh*32 + nt*16 + li; float bb = b1[l*64 + col];
#pragma unroll
        for (int r4 = 0; r4 < 4; ++r4)
          B2[qb*16 + g*4 + r4][col] = fmaxf(acc[nt][r4] + bb, 0.f);
      }
    }
    __syncthreads();

    // ---- ph8: out = (h @ W2 + b2 + res) * mask -> B0 (V^T dead) ----
    { short8 hh[2], hl[2];
#pragma unroll
      for (int kc = 0; kc < 2; ++kc)
        a_frag(&B2[qb*16 + li][kc*32 + g*8], hh[kc], hl[kc]);
      f32x4 acc[2]; mmW2p(hh, hl, Wp, mb + 4, cbh, lane, acc);
#pragma unroll
      for (int nt = 0; nt < 2; ++nt){
        int col = cbh*32 + nt*16 + li; float bb = b2[l*64 + col];
#pragma unroll
        for (int r4 = 0; r4 < 4; ++r4){
          int row = qb*16 + g*4 + r4;
          float m = ((mvec >> row) & 1) ? 1.f : 0.f;
          B0[row][col] = (acc[nt][r4] + bb + B1[row][col]) * m;
        }
      }
    }
  }

  // ---- fused final LN on row 63 -> packed bf16 hi/lo E ----
  __syncthreads();
  if (wid == 0){
    float x = B0[63][lane];
    float mu = wsum(x) * (1.f / 64.f);
    float dv = x - mu;
    float var = wsum(dv * dv) * (1.f / 64.f);
    float o = dv * (1.f / sqrtf(var + EPSV)) * lnfg[lane] + lnfb[lane];
    ushort_t h = f2b(o);
    Eh[b * 64 + lane] = h;
    El[b * 64 + lane] = f2b(o - b2f(h));
  }
}

// --------------------------------------------------------------- scoring ---
// Exact R9 kernel (best config), single launch.
#define LOADA(DH, DL, c) { int er = (c)*64 + w*16 + li;                 \
  DH[0] = *(const short8*)&Eh[er*64 + g*8];                             \
  DH[1] = *(const short8*)&Eh[er*64 + 32 + g*8];                        \
  DL[0] = *(const short8*)&El[er*64 + g*8];                             \
  DL[1] = *(const short8*)&El[er*64 + 32 + g*8]; }

#define CHUNK(c, CAh, CAl, NAh, NAl, PF) {                              \
  if (PF) LOADA(NAh, NAl, (c)+1);                                       \
  f32x4 acc[8];                                                         \
  _Pragma("unroll") for (int nt = 0; nt < 8; ++nt) acc[nt] = (f32x4)(0.f); \
  _Pragma("unroll") for (int kc = 0; kc < 2; ++kc){                     \
    _Pragma("unroll") for (int nt = 0; nt < 8; ++nt){                   \
      short8 bh = TB[nt*2 + kc][lane];                                  \
      short8 bl = TB[16 + nt*2 + kc][lane];                             \
      acc[nt] = __builtin_amdgcn_mfma_f32_16x16x32_bf16(CAh[kc], bh, acc[nt], 0, 0, 0); \
      acc[nt] = __builtin_amdgcn_mfma_f32_16x16x32_bf16(CAh[kc], bl, acc[nt], 0, 0, 0); \
      acc[nt] = __builtin_amdgcn_mfma_f32_16x16x32_bf16(CAl[kc], bh, acc[nt], 0, 0, 0); \
    }}                                                                  \
  _Pragma("unroll") for (int nt = 0; nt < 8; ++nt)                      \
    _Pragma("unroll") for (int r = 0; r < 4; ++r)                       \
      TT[w][g*4 + r][nt*16 + li] = acc[nt][r];                          \
  asm volatile("s_waitcnt lgkmcnt(0)" ::: "memory");                    \
  __builtin_amdgcn_sched_barrier(0);                                    \
  _Pragma("unroll") for (int k = 0; k < 4; ++k){                        \
    int rr = 4*k + g;                                                   \
    size_t rb = (size_t)((c)*64 + w*16 + rr) * NITEMS;                  \
    _Pragma("unroll") for (int h2 = 0; h2 < 2; ++h2){                   \
      int col = i0 + li*8 + h2*4;                                       \
      if (col < NITEMS)                                                 \
        *(float4*)&out[rb + col] = *(const float4*)&TT[w][rr][li*8 + h2*4]; \
    }}                                                                  \
  __builtin_amdgcn_sched_barrier(0); }

__global__ __launch_bounds__(256) void k_score(
    const ushort_t* __restrict__ Eh, const ushort_t* __restrict__ El,
    const float* __restrict__ T, float* __restrict__ out){
  __shared__ short8 TB[32][64];     // 32 KB: frag-ordered T tile (hi/lo)
  __shared__ float TT[4][16][132];  // 33 KB: per-wave transpose tiles
  const int t = threadIdx.x, lane = t & 63, w = t >> 6;  // 4 waves
  const int li = lane & 15, g = lane >> 4;
  const int i0 = blockIdx.x * 128;

  // ---- stage T tile (128 rows) into LDS fragment order, hi/lo bf16 ----
#pragma unroll
  for (int i = 0; i < 8; ++i){
    int e4 = t + 256 * i;            // [128 rows][16 float4-cols]
    int r = e4 >> 4, c4 = e4 & 15;
    int gi = i0 + r;
    float4 v = make_float4(0.f, 0.f, 0.f, 0.f);
    if (gi < NITEMS) v = ((const float4*)(T + (size_t)gi * 64))[c4];
    int nt = r >> 4, li2 = r & 15;
    int kc = c4 >> 3, g2 = (c4 >> 1) & 3, j0 = (c4 & 1) * 4;
    float f[4] = {v.x, v.y, v.z, v.w};
    u64_t ph = 0, pl = 0;
#pragma unroll
    for (int j = 0; j < 4; ++j){
      ushort_t hh = f2b(f[j]);
      ushort_t ll = f2b(f[j] - b2f(hh));
      ph |= (u64_t)hh << (16*j);
      pl |= (u64_t)ll << (16*j);
    }
    *(u64_t*)((ushort_t*)&TB[nt*2 + kc][g2*16 + li2] + j0) = ph;
    *(u64_t*)((ushort_t*)&TB[16 + nt*2 + kc][g2*16 + li2] + j0) = pl;
  }
  __syncthreads();

  // ---- 8 batch chunks, A double-buffered ----
  short8 Ah0[2], Al0[2], Ah1[2], Al1[2];
  LOADA(Ah0, Al0, 0);
  CHUNK(0, Ah0, Al0, Ah1, Al1, 1)
  CHUNK(1, Ah1, Al1, Ah0, Al0, 1)
  CHUNK(2, Ah0, Al0, Ah1, Al1, 1)
  CHUNK(3, Ah1, Al1, Ah0, Al0, 1)
  CHUNK(4, Ah0, Al0, Ah1, Al1, 1)
  CHUNK(5, Ah1, Al1, Ah0, Al0, 1)
  CHUNK(6, Ah0, Al0, Ah1, Al1, 1)
  CHUNK(7, Ah1, Al1, Ah0, Al0, 0)
}

// ----------------------------------------------------------------- launch --
extern "C" void kernel_launch(void* const* d_in, const int* in_sizes, int n_in,
                              void* d_out, int out_size, void* d_ws, size_t ws_size,
                              hipStream_t stream){
  const int*   ids      = (const int*)  d_in[0];
  const float* item_emb = (const float*)d_in[1];
  const float* pos_emb  = (const float*)d_in[2];
  const float* ln1g     = (const float*)d_in[3];
  const float* ln1b     = (const float*)d_in[4];
  const float* Wq       = (const float*)d_in[5];
  const float* bq       = (const float*)d_in[6];
  const float* Wk       = (const float*)d_in[7];
  const float* bk       = (const float*)d_in[8];
  const float* Wv       = (const float*)d_in[9];
  const float* bv       = (const float*)d_in[10];
  const float* ln2g     = (const float*)d_in[11];
  const float* ln2b     = (const float*)d_in[12];
  const float* W1       = (const float*)d_in[13];
  const float* b1       = (const float*)d_in[14];
  const float* W2       = (const float*)d_in[15];
  const float* b2       = (const float*)d_in[16];
  const float* lnfg     = (const float*)d_in[17];
  const float* lnfb     = (const float*)d_in[18];
  const float* items    = (const float*)d_in[19];
  float* out = (float*)d_out;

  ushort_t* Ehp = (ushort_t*)d_ws;                         // 64 KB
  ushort_t* Elp = Ehp + 512 * 64;                          // 64 KB
  short8*   Wp  = (short8*)((char*)d_ws + (256u << 10));   // 160 KB

  k_packw<<<10, 512, 0, stream>>>(Wq, Wk, Wv, W1, W2, Wp);
  k_layers<<<Bsz, 512, 0, stream>>>(ids, item_emb, pos_emb,
      ln1g, ln1b, Wp, bq, bk, bv,
      ln2g, ln2b, b1, b2, lnfg, lnfb, Ehp, Elp);
  k_score<<<1563, 256, 0, stream>>>(Ehp, Elp, items, out);
}

// Round 16
// 154.929 us; speedup vs baseline: 1.9450x; 1.1506x over previous
//
#include <hip/hip_runtime.h>
#include <cstddef>

// SASRec inference. Round 16: k_score store path — per-instruction-contiguous
// 256B bursts (col = (h2*16+li)*4) + nontemporal float4 stores to elide L2
// write-allocate fills on the 410 MB output stream. Everything else = R15.

#define NITEMS 200000
#define Bsz 512
#define Ssz 64
#define Dsz 64
#define EPSV 1e-3f
#define NEGV (-4294967295.0f)   // -2^32 + 1

typedef __attribute__((ext_vector_type(8))) short short8;   // 8 bf16
typedef __attribute__((ext_vector_type(4))) float f32x4;
typedef unsigned short ushort_t;
typedef unsigned long long u64_t;

static __device__ __forceinline__ float wsum(float v){
#pragma unroll
  for (int o = 32; o > 0; o >>= 1) v += __shfl_xor(v, o, 64);
  return v;
}
static __device__ __forceinline__ float wmax(float v){
#pragma unroll
  for (int o = 32; o > 0; o >>= 1) v = fmaxf(v, __shfl_xor(v, o, 64));
  return v;
}

// bf16 round-to-nearest-even (finite inputs only)
static __device__ __forceinline__ ushort_t f2b(float f){
  unsigned u = __float_as_uint(f);
  unsigned r = u + 0x7fffu + ((u >> 16) & 1u);
  return (ushort_t)(r >> 16);
}
static __device__ __forceinline__ float b2f(ushort_t h){
  return __uint_as_float(((unsigned)h) << 16);
}

// 8 consecutive f32 -> bf16 hi/lo fragments (in registers)
static __device__ __forceinline__ void a_frag(const float* __restrict__ p,
    short8& h8, short8& l8){
  float4 v0 = *(const float4*)p, v1 = *(const float4*)(p + 4);
  float f[8] = {v0.x,v0.y,v0.z,v0.w,v1.x,v1.y,v1.z,v1.w};
#pragma unroll
  for (int j = 0; j < 8; ++j){
    ushort_t hh = f2b(f[j]);
    h8[j] = (short)hh;
    l8[j] = (short)f2b(f[j] - b2f(hh));
  }
}

// ----------------------------------------------------------- weight pack ----
__global__ __launch_bounds__(512) void k_packw(const float* __restrict__ Wq,
    const float* __restrict__ Wk, const float* __restrict__ Wv,
    const float* __restrict__ W1, const float* __restrict__ W2,
    short8* __restrict__ Wp){
  const int m = blockIdx.x;            // 0..9
  const int l = m / 5, which = m % 5;
  const float* Ws[5] = {Wq, Wk, Wv, W1, W2};
  const float* Wg = Ws[which] + l * 4096;
  const int t = threadIdx.x;
  const int lane = t & 63, s = t >> 6;           // s = 0..7
  const int li = lane & 15, g = lane >> 4;
  const int cb = s >> 1, kc = s & 1;
  short8 h, lo;
#pragma unroll
  for (int j = 0; j < 8; ++j){
    float f = Wg[(kc*32 + g*8 + j)*64 + cb*16 + li];
    ushort_t hh = f2b(f);
    h[j] = (short)hh;
    lo[j] = (short)f2b(f - b2f(hh));
  }
  Wp[(m*16 + s)*64 + lane] = h;
  Wp[(m*16 + 8 + s)*64 + lane] = lo;
}

// 2-tile GEMM strip vs PACKED weight frags (8 coalesced 16B loads + MFMA)
static __device__ __forceinline__ void mmW2p(const short8 ah[2], const short8 al[2],
    const short8* __restrict__ Wp, int m, int cbh, int lane, f32x4 acc[2]){
#pragma unroll
  for (int nt = 0; nt < 2; ++nt){
    acc[nt] = (f32x4)(0.f);
#pragma unroll
    for (int kc = 0; kc < 2; ++kc){
      int s = (cbh*2 + nt)*2 + kc;
      short8 bh = Wp[(m*16 + s)*64 + lane];
      short8 bl = Wp[(m*16 + 8 + s)*64 + lane];
      acc[nt] = __builtin_amdgcn_mfma_f32_16x16x32_bf16(ah[kc], bh, acc[nt], 0, 0, 0);
      acc[nt] = __builtin_amdgcn_mfma_f32_16x16x32_bf16(ah[kc], bl, acc[nt], 0, 0, 0);
      acc[nt] = __builtin_amdgcn_mfma_f32_16x16x32_bf16(al[kc], bh, acc[nt], 0, 0, 0);
    }
  }
}

// 2-tile GEMM strip: A-frags in registers, B rows from f32 LDS ([n][k] layout)
static __device__ __forceinline__ void mmB2(const short8 ah[2], const short8 al[2],
    const float (*__restrict__ B)[68], int cbh, int li, int g, f32x4 acc[2]){
#pragma unroll
  for (int nt = 0; nt < 2; ++nt){
    acc[nt] = (f32x4)(0.f);
#pragma unroll
    for (int kc = 0; kc < 2; ++kc){
      short8 bh, bl;
      a_frag(&B[cbh*32 + nt*16 + li][kc*32 + g*8], bh, bl);
      acc[nt] = __builtin_amdgcn_mfma_f32_16x16x32_bf16(ah[kc], bh, acc[nt], 0, 0, 0);
      acc[nt] = __builtin_amdgcn_mfma_f32_16x16x32_bf16(ah[kc], bl, acc[nt], 0, 0, 0);
      acc[nt] = __builtin_amdgcn_mfma_f32_16x16x32_bf16(al[kc], bh, acc[nt], 0, 0, 0);
    }
  }
}

// ------------------------------------------------------ fused block layers --
__global__ __launch_bounds__(512, 4) void k_layers(const int* __restrict__ ids,
    const float* __restrict__ item_emb, const float* __restrict__ pos_emb,
    const float* __restrict__ ln1g, const float* __restrict__ ln1b,
    const short8* __restrict__ Wp,
    const float* __restrict__ bq, const float* __restrict__ bk,
    const float* __restrict__ bv,
    const float* __restrict__ ln2g, const float* __restrict__ ln2b,
    const float* __restrict__ b1, const float* __restrict__ b2,
    const float* __restrict__ lnfg, const float* __restrict__ lnfb,
    ushort_t* __restrict__ Eh, ushort_t* __restrict__ El){
  __shared__ float B0[64][68];   // seq -> V^T -> (next) seq
  __shared__ float B1[64][68];   // xq (LN1 out) -> res (LN2 out)
  __shared__ float B2[64][68];   // Q -> scores/P -> FFN hidden
  __shared__ float B3[64][68];   // K -> x (attn+residual)

  const int t = threadIdx.x;
  const int lane = t & 63, wid = t >> 6;        // 8 waves
  const int li = lane & 15, g = lane >> 4;
  const int qb = wid & 3, cbh = wid >> 2;       // rows qb*16.., cols cbh*32..+31
  const int b = blockIdx.x;

  // ---- phase 0 (fused embed): gather + pos -> B0 (f32); ballot mask ----
#pragma unroll
  for (int it = 0; it < 2; ++it){
    int e4 = t + 512 * it;
    int r = e4 >> 4, c4 = e4 & 15, c = c4 * 4;
    int id = ids[b * Ssz + r];
    float4 v = make_float4(0.f, 0.f, 0.f, 0.f);
    if (id != NITEMS){
      float4 a = ((const float4*)(item_emb + (size_t)id * 64))[c4];
      float4 p = ((const float4*)(pos_emb + r * 64))[c4];
      v = make_float4(a.x + p.x, a.y + p.y, a.z + p.z, a.w + p.w);
    }
    *(float4*)&B0[r][c] = v;
  }
  const int myid = ids[b * Ssz + lane];
  const u64_t mvec = __ballot(myid != NITEMS);   // bit r = row r valid

  for (int l = 0; l < 2; ++l){
    const int mb = l * 5;
    __syncthreads();   // fences phase-0 (l=0) / previous layer-out (l=1)

    // ---- LN1: B0 -> B1 (8 rows/wave) ----
    for (int r = wid; r < 64; r += 8){
      float x = B0[r][lane];
      float mu = wsum(x) * (1.f / 64.f);
      float dv = x - mu;
      float var = wsum(dv * dv) * (1.f / 64.f);
      B1[r][lane] = dv * (1.f / sqrtf(var + EPSV)) * ln1g[l*64 + lane] + ln1b[l*64 + lane];
    }
    __syncthreads();

    // ---- ph1: A-frags of seq (B0) and LN1 (B1); Q -> B2, K -> B3 ----
    short8 a0h[2], a0l[2], a1h[2], a1l[2];
#pragma unroll
    for (int kc = 0; kc < 2; ++kc){
      a_frag(&B0[qb*16 + li][kc*32 + g*8], a0h[kc], a0l[kc]);
      a_frag(&B1[qb*16 + li][kc*32 + g*8], a1h[kc], a1l[kc]);
    }
    { f32x4 acc[2]; mmW2p(a1h, a1l, Wp, mb + 0, cbh, lane, acc);
#pragma unroll
      for (int nt = 0; nt < 2; ++nt){
        int col = cbh*32 + nt*16 + li; float bb = bq[l*64 + col];
#pragma unroll
        for (int r4 = 0; r4 < 4; ++r4) B2[qb*16 + g*4 + r4][col] = acc[nt][r4] + bb;
      }
    }
    { f32x4 acc[2]; mmW2p(a0h, a0l, Wp, mb + 1, cbh, lane, acc);
#pragma unroll
      for (int nt = 0; nt < 2; ++nt){
        int col = cbh*32 + nt*16 + li; float bb = bk[l*64 + col];
#pragma unroll
        for (int r4 = 0; r4 < 4; ++r4) B3[qb*16 + g*4 + r4][col] = acc[nt][r4] + bb;
      }
    }
    __syncthreads();

    // ---- ph2: V (from seq frags) -> B0 transposed; snapshot Q frags ----
    { f32x4 acc[2]; mmW2p(a0h, a0l, Wp, mb + 2, cbh, lane, acc);
#pragma unroll
      for (int nt = 0; nt < 2; ++nt){
        int col = cbh*32 + nt*16 + li; float bb = bv[l*64 + col];
#pragma unroll
        for (int r4 = 0; r4 < 4; ++r4) B0[col][qb*16 + g*4 + r4] = acc[nt][r4] + bb;
      }
    }
    short8 qh[2], ql[2];
#pragma unroll
    for (int kc = 0; kc < 2; ++kc)
      a_frag(&B2[qb*16 + li][kc*32 + g*8], qh[kc], ql[kc]);
    __syncthreads();

    // ---- ph3: scores = Q @ K^T -> B2 (Q dead, snapshotted) ----
    { f32x4 acc[2]; mmB2(qh, ql, B3, cbh, li, g, acc);
#pragma unroll
      for (int nt = 0; nt < 2; ++nt){
        int col = cbh*32 + nt*16 + li;
#pragma unroll
        for (int r4 = 0; r4 < 4; ++r4) B2[qb*16 + g*4 + r4][col] = acc[nt][r4];
      }
    }
    __syncthreads();

    // ---- ph4: masked softmax in place (B2) ----
    for (int r = wid; r < 64; r += 8){
      float raw = B2[r][lane];
      bool valid = (lane <= r) && ((mvec >> lane) & 1);
      float sc = valid ? raw * 0.125f : NEGV;
      float m = wmax(sc);
      float e = __expf(sc - m);
      float ssumv = wsum(e);
      float qm = ((mvec >> r) & 1) ? 1.f : 0.f;
      B2[r][lane] = (e / ssumv) * qm;
    }
    __syncthreads();

    // ---- ph5: x = P @ V + xq -> B3 (K dead) ----
    { short8 pfh[2], pfl[2];
#pragma unroll
      for (int kc = 0; kc < 2; ++kc)
        a_frag(&B2[qb*16 + li][kc*32 + g*8], pfh[kc], pfl[kc]);
      f32x4 acc[2]; mmB2(pfh, pfl, B0, cbh, li, g, acc);
#pragma unroll
      for (int nt = 0; nt < 2; ++nt){
        int col = cbh*32 + nt*16 + li;
#pragma unroll
        for (int r4 = 0; r4 < 4; ++r4){
          int row = qb*16 + g*4 + r4;
          B3[row][col] = acc[nt][r4] + B1[row][col];
        }
      }
    }
    __syncthreads();

    // ---- ph6: LN2: B3 -> B1 (xq dead) ----
    for (int r = wid; r < 64; r += 8){
      float x = B3[r][lane];
      float mu = wsum(x) * (1.f / 64.f);
      float dv = x - mu;
      float var = wsum(dv * dv) * (1.f / 64.f);
      B1[r][lane] = dv * (1.f / sqrtf(var + EPSV)) * ln2g[l*64 + lane] + ln2b[l*64 + lane];
    }
    __syncthreads();

    // ---- ph7: h = relu(res @ W1 + b1) -> B2 (P dead) ----
    { short8 rh[2], rl[2];
#pragma unroll
      for (int kc = 0; kc < 2; ++kc)
        a_frag(&B1[qb*16 + li][kc*32 + g*8], rh[kc], rl[kc]);
      f32x4 acc[2]; mmW2p(rh, rl, Wp, mb + 3, cbh, lane, acc);
#pragma unroll
      for (int nt = 0; nt < 2; ++nt){
        int col = cbh*32 + nt*16 + li; float bb = b1[l*64 + col];
#pragma unroll
        for (int r4 = 0; r4 < 4; ++r4)
          B2[qb*16 + g*4 + r4][col] = fmaxf(acc[nt][r4] + bb, 0.f);
      }
    }
    __syncthreads();

    // ---- ph8: out = (h @ W2 + b2 + res) * mask -> B0 (V^T dead) ----
    { short8 hh[2], hl[2];
#pragma unroll
      for (int kc = 0; kc < 2; ++kc)
        a_frag(&B2[qb*16 + li][kc*32 + g*8], hh[kc], hl[kc]);
      f32x4 acc[2]; mmW2p(hh, hl, Wp, mb + 4, cbh, lane, acc);
#pragma unroll
      for (int nt = 0; nt < 2; ++nt){
        int col = cbh*32 + nt*16 + li; float bb = b2[l*64 + col];
#pragma unroll
        for (int r4 = 0; r4 < 4; ++r4){
          int row = qb*16 + g*4 + r4;
          float m = ((mvec >> row) & 1) ? 1.f : 0.f;
          B0[row][col] = (acc[nt][r4] + bb + B1[row][col]) * m;
        }
      }
    }
  }

  // ---- fused final LN on row 63 -> packed bf16 hi/lo E ----
  __syncthreads();
  if (wid == 0){
    float x = B0[63][lane];
    float mu = wsum(x) * (1.f / 64.f);
    float dv = x - mu;
    float var = wsum(dv * dv) * (1.f / 64.f);
    float o = dv * (1.f / sqrtf(var + EPSV)) * lnfg[lane] + lnfb[lane];
    ushort_t h = f2b(o);
    Eh[b * 64 + lane] = h;
    El[b * 64 + lane] = f2b(o - b2f(h));
  }
}

// --------------------------------------------------------------- scoring ---
// R9 structure; store path: per-instruction-contiguous 256B + NT stores.
#define LOADA(DH, DL, c) { int er = (c)*64 + w*16 + li;                 \
  DH[0] = *(const short8*)&Eh[er*64 + g*8];                             \
  DH[1] = *(const short8*)&Eh[er*64 + 32 + g*8];                        \
  DL[0] = *(const short8*)&El[er*64 + g*8];                             \
  DL[1] = *(const short8*)&El[er*64 + 32 + g*8]; }

#define CHUNK(c, CAh, CAl, NAh, NAl, PF) {                              \
  if (PF) LOADA(NAh, NAl, (c)+1);                                       \
  f32x4 acc[8];                                                         \
  _Pragma("unroll") for (int nt = 0; nt < 8; ++nt) acc[nt] = (f32x4)(0.f); \
  _Pragma("unroll") for (int kc = 0; kc < 2; ++kc){                     \
    _Pragma("unroll") for (int nt = 0; nt < 8; ++nt){                   \
      short8 bh = TB[nt*2 + kc][lane];                                  \
      short8 bl = TB[16 + nt*2 + kc][lane];                             \
      acc[nt] = __builtin_amdgcn_mfma_f32_16x16x32_bf16(CAh[kc], bh, acc[nt], 0, 0, 0); \
      acc[nt] = __builtin_amdgcn_mfma_f32_16x16x32_bf16(CAh[kc], bl, acc[nt], 0, 0, 0); \
      acc[nt] = __builtin_amdgcn_mfma_f32_16x16x32_bf16(CAl[kc], bh, acc[nt], 0, 0, 0); \
    }}                                                                  \
  _Pragma("unroll") for (int nt = 0; nt < 8; ++nt)                      \
    _Pragma("unroll") for (int r = 0; r < 4; ++r)                       \
      TT[w][g*4 + r][nt*16 + li] = acc[nt][r];                          \
  asm volatile("s_waitcnt lgkmcnt(0)" ::: "memory");                    \
  __builtin_amdgcn_sched_barrier(0);                                    \
  _Pragma("unroll") for (int k = 0; k < 4; ++k){                        \
    int rr = 4*k + g;                                                   \
    size_t rb = (size_t)((c)*64 + w*16 + rr) * NITEMS;                  \
    _Pragma("unroll") for (int h2 = 0; h2 < 2; ++h2){                   \
      int cidx = (h2*16 + li) * 4;                                      \
      int col = i0 + cidx;                                              \
      if (col < NITEMS){                                                \
        f32x4 v = *(const f32x4*)&TT[w][rr][cidx];                      \
        __builtin_nontemporal_store(v, (f32x4*)&out[rb + col]);         \
      }                                                                 \
    }}                                                                  \
  __builtin_amdgcn_sched_barrier(0); }

__global__ __launch_bounds__(256) void k_score(
    const ushort_t* __restrict__ Eh, const ushort_t* __restrict__ El,
    const float* __restrict__ T, float* __restrict__ out){
  __shared__ short8 TB[32][64];     // 32 KB: frag-ordered T tile (hi/lo)
  __shared__ float TT[4][16][132];  // 33 KB: per-wave transpose tiles
  const int t = threadIdx.x, lane = t & 63, w = t >> 6;  // 4 waves
  const int li = lane & 15, g = lane >> 4;
  const int i0 = blockIdx.x * 128;

  // ---- stage T tile (128 rows) into LDS fragment order, hi/lo bf16 ----
#pragma unroll
  for (int i = 0; i < 8; ++i){
    int e4 = t + 256 * i;            // [128 rows][16 float4-cols]
    int r = e4 >> 4, c4 = e4 & 15;
    int gi = i0 + r;
    float4 v = make_float4(0.f, 0.f, 0.f, 0.f);
    if (gi < NITEMS) v = ((const float4*)(T + (size_t)gi * 64))[c4];
    int nt = r >> 4, li2 = r & 15;
    int kc = c4 >> 3, g2 = (c4 >> 1) & 3, j0 = (c4 & 1) * 4;
    float f[4] = {v.x, v.y, v.z, v.w};
    u64_t ph = 0, pl = 0;
#pragma unroll
    for (int j = 0; j < 4; ++j){
      ushort_t hh = f2b(f[j]);
      ushort_t ll = f2b(f[j] - b2f(hh));
      ph |= (u64_t)hh << (16*j);
      pl |= (u64_t)ll << (16*j);
    }
    *(u64_t*)((ushort_t*)&TB[nt*2 + kc][g2*16 + li2] + j0) = ph;
    *(u64_t*)((ushort_t*)&TB[16 + nt*2 + kc][g2*16 + li2] + j0) = pl;
  }
  __syncthreads();

  // ---- 8 batch chunks, A double-buffered ----
  short8 Ah0[2], Al0[2], Ah1[2], Al1[2];
  LOADA(Ah0, Al0, 0);
  CHUNK(0, Ah0, Al0, Ah1, Al1, 1)
  CHUNK(1, Ah1, Al1, Ah0, Al0, 1)
  CHUNK(2, Ah0, Al0, Ah1, Al1, 1)
  CHUNK(3, Ah1, Al1, Ah0, Al0, 1)
  CHUNK(4, Ah0, Al0, Ah1, Al1, 1)
  CHUNK(5, Ah1, Al1, Ah0, Al0, 1)
  CHUNK(6, Ah0, Al0, Ah1, Al1, 1)
  CHUNK(7, Ah1, Al1, Ah0, Al0, 0)
}

// ----------------------------------------------------------------- launch --
extern "C" void kernel_launch(void* const* d_in, const int* in_sizes, int n_in,
                              void* d_out, int out_size, void* d_ws, size_t ws_size,
                              hipStream_t stream){
  const int*   ids      = (const int*)  d_in[0];
  const float* item_emb = (const float*)d_in[1];
  const float* pos_emb  = (const float*)d_in[2];
  const float* ln1g     = (const float*)d_in[3];
  const float* ln1b     = (const float*)d_in[4];
  const float* Wq       = (const float*)d_in[5];
  const float* bq       = (const float*)d_in[6];
  const float* Wk       = (const float*)d_in[7];
  const float* bk       = (const float*)d_in[8];
  const float* Wv       = (const float*)d_in[9];
  const float* bv       = (const float*)d_in[10];
  const float* ln2g     = (const float*)d_in[11];
  const float* ln2b     = (const float*)d_in[12];
  const float* W1       = (const float*)d_in[13];
  const float* b1       = (const float*)d_in[14];
  const float* W2       = (const float*)d_in[15];
  const float* b2       = (const float*)d_in[16];
  const float* lnfg     = (const float*)d_in[17];
  const float* lnfb     = (const float*)d_in[18];
  const float* items    = (const float*)d_in[19];
  float* out = (float*)d_out;

  ushort_t* Ehp = (ushort_t*)d_ws;                         // 64 KB
  ushort_t* Elp = Ehp + 512 * 64;                          // 64 KB
  short8*   Wp  = (short8*)((char*)d_ws + (256u << 10));   // 160 KB

  k_packw<<<10, 512, 0, stream>>>(Wq, Wk, Wv, W1, W2, Wp);
  k_layers<<<Bsz, 512, 0, stream>>>(ids, item_emb, pos_emb,
      ln1g, ln1b, Wp, bq, bk, bv,
      ln2g, ln2b, b1, b2, lnfg, lnfb, Ehp, Elp);
  k_score<<<1563, 256, 0, stream>>>(Ehp, Elp, items, out);
}